// Round 3
// baseline (797.151 us; speedup 1.0000x reference)
//
#include <hip/hip_runtime.h>
#include <hip/hip_bf16.h>

// Problem constants (match reference)
#define N_NODES 100000
#define N_EDGES 1600000
#define N_GRAPHS 128

// ---------------- CSR build ----------------

// 8 edges per thread: 8 independent atomics in flight (latency-bound fix)
__global__ void k_count(const int* __restrict__ col, int* __restrict__ deg) {
    int t = blockIdx.x * blockDim.x + threadIdx.x;
    int e0 = t * 8;
    if (e0 >= N_EDGES) return;
    const int4 c0 = *reinterpret_cast<const int4*>(col + e0);
    const int4 c1 = *reinterpret_cast<const int4*>(col + e0 + 4);
    atomicAdd(&deg[c0.x], 1); atomicAdd(&deg[c0.y], 1);
    atomicAdd(&deg[c0.z], 1); atomicAdd(&deg[c0.w], 1);
    atomicAdd(&deg[c1.x], 1); atomicAdd(&deg[c1.y], 1);
    atomicAdd(&deg[c1.z], 1); atomicAdd(&deg[c1.w], 1);
}

// per-block exclusive scan over 256 PADDED degrees (pad to multiple of 8)
__global__ void k_scan1(const int* __restrict__ deg, int* __restrict__ offs,
                        int* __restrict__ bsums) {
    __shared__ int s[256];
    int t = threadIdx.x;
    int gi = blockIdx.x * 256 + t;
    int v = (gi < N_NODES) ? ((deg[gi] + 7) & ~7) : 0;
    s[t] = v; __syncthreads();
    for (int off = 1; off < 256; off <<= 1) {
        int a = (t >= off) ? s[t - off] : 0;
        __syncthreads();
        s[t] += a;
        __syncthreads();
    }
    if (gi < N_NODES) offs[gi] = s[t] - v;   // exclusive
    if (t == 255) bsums[blockIdx.x] = s[255];
}

// scan the block sums (single block); also fill the sentinel zpad segment
__global__ void k_scan2(int* __restrict__ bsums, int nb, int* __restrict__ zpad) {
    __shared__ int s[512];
    int t = threadIdx.x;
    if (t < 8) zpad[t] = N_NODES;            // sentinel -> zero feature row
    int v = (t < nb) ? bsums[t] : 0;
    s[t] = v; __syncthreads();
    for (int off = 1; off < 512; off <<= 1) {
        int a = (t >= off) ? s[t - off] : 0;
        __syncthreads();
        s[t] += a;
        __syncthreads();
    }
    if (t < nb) bsums[t] = s[t] - v;         // exclusive
}

// finalize offsets, cursors, dinv; fill padding slots with the sentinel
// zero-row index (N_NODES). Safe before k_scatter: disjoint positions.
__global__ void k_scan3(int* __restrict__ offs, const int* __restrict__ bsums,
                        const int* __restrict__ deg, int* __restrict__ cursor,
                        float* __restrict__ dinv, int* __restrict__ csr) {
    int gi = blockIdx.x * 256 + threadIdx.x;
    if (gi >= N_NODES) return;
    int off = offs[gi] + bsums[blockIdx.x];
    offs[gi] = off;
    cursor[gi] = off;
    int d = deg[gi];
    dinv[gi] = (d > 0) ? rsqrtf((float)d) : 0.0f;
    int pd = (d + 7) & ~7;
    for (int j = d; j < pd; j++) csr[off + j] = N_NODES;
}

// 8 edges per thread: 8 independent atomic+store pairs in flight
__global__ void k_scatter(const int* __restrict__ row, const int* __restrict__ col,
                          int* __restrict__ cursor, int* __restrict__ csr) {
    int t = blockIdx.x * blockDim.x + threadIdx.x;
    int e0 = t * 8;
    if (e0 >= N_EDGES) return;
    const int4 r0 = *reinterpret_cast<const int4*>(row + e0);
    const int4 r1 = *reinterpret_cast<const int4*>(row + e0 + 4);
    const int4 c0 = *reinterpret_cast<const int4*>(col + e0);
    const int4 c1 = *reinterpret_cast<const int4*>(col + e0 + 4);
    int p0 = atomicAdd(&cursor[c0.x], 1);
    int p1 = atomicAdd(&cursor[c0.y], 1);
    int p2 = atomicAdd(&cursor[c0.z], 1);
    int p3 = atomicAdd(&cursor[c0.w], 1);
    int p4 = atomicAdd(&cursor[c1.x], 1);
    int p5 = atomicAdd(&cursor[c1.y], 1);
    int p6 = atomicAdd(&cursor[c1.z], 1);
    int p7 = atomicAdd(&cursor[c1.w], 1);
    csr[p0] = r0.x; csr[p1] = r0.y; csr[p2] = r0.z; csr[p3] = r0.w;
    csr[p4] = r1.x; csr[p5] = r1.y; csr[p6] = r1.z; csr[p7] = r1.w;
}

// ---------------- tall-skinny GEMM: H[n] = dinv[n] * (X[n,:] @ W) ----------------
// block = 256 threads = 4 waves; each wave does 8 nodes, lane = output channel.

template <int CIN>
__global__ __launch_bounds__(256) void k_gemm(const float* __restrict__ X,
                                              const float* __restrict__ W,
                                              const float* __restrict__ dinv,
                                              float* __restrict__ H) {
    constexpr int STR = CIN + 4;               // pad to break bank alias
    __shared__ float sW[64 * STR];             // W transposed: sW[c*STR + k]
    __shared__ float sX[32 * STR];             // 32 nodes of X
    const int t = threadIdx.x;

    for (int idx = t; idx < CIN * 64; idx += 256) {
        int k = idx >> 6, c = idx & 63;
        sW[c * STR + k] = W[idx];
    }
    const int nb = blockIdx.x * 32;
    for (int f4 = t; f4 < 32 * CIN / 4; f4 += 256) {
        int f = f4 * 4;
        int nl = f / CIN, kk = f % CIN;
        const float4 v = *reinterpret_cast<const float4*>(X + (size_t)(nb + nl) * CIN + kk);
        *reinterpret_cast<float4*>(&sX[nl * STR + kk]) = v;
    }
    __syncthreads();

    const int wave = t >> 6, lane = t & 63;
    const int n0 = wave * 8;
    float acc[8] = {0.f,0.f,0.f,0.f,0.f,0.f,0.f,0.f};
    for (int kq = 0; kq < CIN; kq += 4) {
        const float4 w4 = *reinterpret_cast<const float4*>(&sW[lane * STR + kq]);
        #pragma unroll
        for (int n = 0; n < 8; n++) {
            const float4 x4 = *reinterpret_cast<const float4*>(&sX[(n0 + n) * STR + kq]);
            acc[n] += w4.x * x4.x + w4.y * x4.y + w4.z * x4.z + w4.w * x4.w;
        }
    }
    #pragma unroll
    for (int n = 0; n < 8; n++) {
        H[(size_t)(nb + n0 + n) * 64 + lane] = acc[n] * dinv[nb + n0 + n];
    }
}

// ---------------- propagation: Hout[v] = dinv[v] * sum_e Hin[row_e] + bias ----------------
// 4 nodes per wave, lane = channel, branchless inner loop with up to
// 32 independent gathers in flight. Inactive node slots read the
// L1-resident sentinel zpad segment (rows -> zero feature row).

__global__ __launch_bounds__(256) void k_prop(const float* __restrict__ Hin,
                                              const int* __restrict__ csr,
                                              const int* __restrict__ offs,
                                              const int* __restrict__ deg,
                                              const float* __restrict__ dinv,
                                              const float* __restrict__ bias,
                                              const int* __restrict__ zpad,
                                              float* __restrict__ Hout) {
    const int wave = threadIdx.x >> 6, lane = threadIdx.x & 63;
    const int vbase = (blockIdx.x * 4 + wave) * 4;   // 4 nodes per wave
    int st[4], cp[4];
    float acc[4] = {0.f, 0.f, 0.f, 0.f};
    int cmax = 0;
    #pragma unroll
    for (int n = 0; n < 4; n++) {
        st[n] = offs[vbase + n];
        cp[n] = (deg[vbase + n] + 7) & ~7;
        cmax = max(cmax, cp[n]);
    }
    for (int j = 0; j < cmax; j += 8) {
        const int* ep0 = (j < cp[0]) ? csr + st[0] + j : zpad;
        const int* ep1 = (j < cp[1]) ? csr + st[1] + j : zpad;
        const int* ep2 = (j < cp[2]) ? csr + st[2] + j : zpad;
        const int* ep3 = (j < cp[3]) ? csr + st[3] + j : zpad;
        int4 qa[4], qb[4];
        qa[0] = *reinterpret_cast<const int4*>(ep0);
        qb[0] = *reinterpret_cast<const int4*>(ep0 + 4);
        qa[1] = *reinterpret_cast<const int4*>(ep1);
        qb[1] = *reinterpret_cast<const int4*>(ep1 + 4);
        qa[2] = *reinterpret_cast<const int4*>(ep2);
        qb[2] = *reinterpret_cast<const int4*>(ep2 + 4);
        qa[3] = *reinterpret_cast<const int4*>(ep3);
        qb[3] = *reinterpret_cast<const int4*>(ep3 + 4);
        #pragma unroll
        for (int n = 0; n < 4; n++) {
            float s0 = Hin[(size_t)qa[n].x * 64 + lane];
            float s1 = Hin[(size_t)qa[n].y * 64 + lane];
            float s2 = Hin[(size_t)qa[n].z * 64 + lane];
            float s3 = Hin[(size_t)qa[n].w * 64 + lane];
            float s4 = Hin[(size_t)qb[n].x * 64 + lane];
            float s5 = Hin[(size_t)qb[n].y * 64 + lane];
            float s6 = Hin[(size_t)qb[n].z * 64 + lane];
            float s7 = Hin[(size_t)qb[n].w * 64 + lane];
            acc[n] += ((s0 + s1) + (s2 + s3)) + ((s4 + s5) + (s6 + s7));
        }
    }
    #pragma unroll
    for (int n = 0; n < 4; n++) {
        const int v = vbase + n;
        Hout[(size_t)v * 64 + lane] = dinv[v] * acc[n] + bias[lane];
    }
}

// ---------------- pooling ----------------

__global__ void k_pool(const float* __restrict__ H, const int* __restrict__ batch,
                       float* __restrict__ gsums) {
    const int gw = (blockIdx.x * blockDim.x + threadIdx.x) >> 6;
    const int lane = threadIdx.x & 63;
    const int nwaves = (gridDim.x * blockDim.x) >> 6;
    const int chunk = (N_NODES + nwaves - 1) / nwaves;
    int v0 = gw * chunk;
    int v1 = min(v0 + chunk, N_NODES);
    if (v0 >= v1) return;
    float acc = 0.f;
    int cur = batch[v0];
    for (int v = v0; v < v1; v++) {
        int g = batch[v];
        if (g != cur) {
            atomicAdd(&gsums[cur * 64 + lane], acc);
            acc = 0.f; cur = g;
        }
        acc += H[(size_t)v * 64 + lane];
    }
    atomicAdd(&gsums[cur * 64 + lane], acc);
}

__global__ void k_final(const float* __restrict__ gsums, const int* __restrict__ batch,
                        const float* __restrict__ Wl, const float* __restrict__ bl,
                        float* __restrict__ out) {
    __shared__ int scnt[128];
    int t = threadIdx.x;
    int lo = 0, hi = N_NODES;
    while (lo < hi) { int mid = (lo + hi) >> 1; if (batch[mid] < t) lo = mid + 1; else hi = mid; }
    int a = lo;
    lo = 0; hi = N_NODES;
    while (lo < hi) { int mid = (lo + hi) >> 1; if (batch[mid] < t + 1) lo = mid + 1; else hi = mid; }
    scnt[t] = lo - a;
    __syncthreads();
    for (int off = 64; off > 0; off >>= 1) {
        if (t < off) scnt[t] = max(scnt[t], scnt[t + off]);
        __syncthreads();
    }
    float nmax = (float)scnt[0];
    float s = 0.f;
    for (int c = 0; c < 64; c++) s += gsums[(size_t)t * 64 + c] * Wl[c];
    out[t] = s / nmax + bl[0];
}

// ---------------- launch ----------------

extern "C" void kernel_launch(void* const* d_in, const int* in_sizes, int n_in,
                              void* d_out, int out_size, void* d_ws, size_t ws_size,
                              hipStream_t stream) {
    const float* x    = (const float*)d_in[0];
    const int*   ei   = (const int*)d_in[1];     // [2, E] int32
    const int*   batch= (const int*)d_in[2];
    const float* W1 = (const float*)d_in[3];  const float* b1 = (const float*)d_in[4];
    const float* W2 = (const float*)d_in[5];  const float* b2 = (const float*)d_in[6];
    const float* W3 = (const float*)d_in[7];  const float* b3 = (const float*)d_in[8];
    const float* W4 = (const float*)d_in[9];  const float* b4 = (const float*)d_in[10];
    const float* Wl = (const float*)d_in[11]; const float* bl = (const float*)d_in[12];
    float* out = (float*)d_out;

    const int* row = ei;
    const int* col = ei + N_EDGES;

    // workspace layout (256B aligned blocks)
    char* ws = (char*)d_ws;
    size_t off = 0;
    auto alloc = [&](size_t bytes) {
        void* p = ws + off;
        off = (off + bytes + 255) & ~(size_t)255;
        return p;
    };
    int*   deg     = (int*)alloc(N_NODES * 4);
    int*   offs    = (int*)alloc(N_NODES * 4);
    int*   cursor  = (int*)alloc(N_NODES * 4);
    float* dinv    = (float*)alloc(N_NODES * 4);
    int*   bsums   = (int*)alloc(512 * 4);
    int*   zpad    = (int*)alloc(8 * 4);
    int*   csr     = (int*)alloc(((size_t)N_EDGES + 8 * N_NODES) * 4);  // padded
    float* h_a     = (float*)alloc((size_t)(N_NODES + 1) * 64 * 4);     // +1 zero row
    float* h_b     = (float*)alloc((size_t)(N_NODES + 1) * 64 * 4);
    float* gsums   = (float*)alloc(N_GRAPHS * 64 * 4);

    const int SCAN_BLOCKS = (N_NODES + 255) / 256;   // 391

    hipMemsetAsync(deg, 0, N_NODES * 4, stream);
    hipMemsetAsync(gsums, 0, N_GRAPHS * 64 * 4, stream);
    hipMemsetAsync(h_a + (size_t)N_NODES * 64, 0, 64 * 4, stream);
    hipMemsetAsync(h_b + (size_t)N_NODES * 64, 0, 64 * 4, stream);

    const int EDGE_THREADS = N_EDGES / 8;            // 200000
    k_count<<<(EDGE_THREADS + 255) / 256, 256, 0, stream>>>(col, deg);
    k_scan1<<<SCAN_BLOCKS, 256, 0, stream>>>(deg, offs, bsums);
    k_scan2<<<1, 512, 0, stream>>>(bsums, SCAN_BLOCKS, zpad);
    k_scan3<<<SCAN_BLOCKS, 256, 0, stream>>>(offs, bsums, deg, cursor, dinv, csr);
    k_scatter<<<(EDGE_THREADS + 255) / 256, 256, 0, stream>>>(row, col, cursor, csr);

    // layer 1: h_a = dinv * (x @ W1) ; h_b = dinv * prop(h_a) + b1
    k_gemm<128><<<N_NODES / 32, 256, 0, stream>>>(x, W1, dinv, h_a);
    k_prop<<<N_NODES / 16, 256, 0, stream>>>(h_a, csr, offs, deg, dinv, b1, zpad, h_b);
    // layer 2
    k_gemm<64><<<N_NODES / 32, 256, 0, stream>>>(h_b, W2, dinv, h_a);
    k_prop<<<N_NODES / 16, 256, 0, stream>>>(h_a, csr, offs, deg, dinv, b2, zpad, h_b);
    // layer 3
    k_gemm<64><<<N_NODES / 32, 256, 0, stream>>>(h_b, W3, dinv, h_a);
    k_prop<<<N_NODES / 16, 256, 0, stream>>>(h_a, csr, offs, deg, dinv, b3, zpad, h_b);
    // layer 4
    k_gemm<64><<<N_NODES / 32, 256, 0, stream>>>(h_b, W4, dinv, h_a);
    k_prop<<<N_NODES / 16, 256, 0, stream>>>(h_a, csr, offs, deg, dinv, b4, zpad, h_b);

    // pooling + readout
    k_pool<<<98, 256, 0, stream>>>(h_b, batch, gsums);
    k_final<<<1, 128, 0, stream>>>(gsums, batch, Wl, bl, out);
}

// Round 4
// 786.810 us; speedup vs baseline: 1.0131x; 1.0131x over previous
//
#include <hip/hip_runtime.h>
#include <hip/hip_bf16.h>

// Problem constants (match reference)
#define N_NODES 100000
#define N_EDGES 1600000
#define N_GRAPHS 128
#define PAD 16   // one atomic counter per 64B line

// ---------------- CSR build ----------------

// one edge per thread; counters padded to one per 64B line to avoid
// same-line atomic serialization at the TCC
__global__ void k_count(const int* __restrict__ col, int* __restrict__ deg_p) {
    int e = blockIdx.x * blockDim.x + threadIdx.x;
    if (e < N_EDGES) atomicAdd(&deg_p[col[e] * PAD], 1);
}

// per-block exclusive scan over 256 PADDED degrees (pad to multiple of 8)
__global__ void k_scan1(const int* __restrict__ deg_p, int* __restrict__ offs,
                        int* __restrict__ bsums) {
    __shared__ int s[256];
    int t = threadIdx.x;
    int gi = blockIdx.x * 256 + t;
    int v = (gi < N_NODES) ? ((deg_p[gi * PAD] + 7) & ~7) : 0;
    s[t] = v; __syncthreads();
    for (int off = 1; off < 256; off <<= 1) {
        int a = (t >= off) ? s[t - off] : 0;
        __syncthreads();
        s[t] += a;
        __syncthreads();
    }
    if (gi < N_NODES) offs[gi] = s[t] - v;   // exclusive
    if (t == 255) bsums[blockIdx.x] = s[255];
}

// scan the block sums (single block)
__global__ void k_scan2(int* __restrict__ bsums, int nb) {
    __shared__ int s[512];
    int t = threadIdx.x;
    int v = (t < nb) ? bsums[t] : 0;
    s[t] = v; __syncthreads();
    for (int off = 1; off < 512; off <<= 1) {
        int a = (t >= off) ? s[t - off] : 0;
        __syncthreads();
        s[t] += a;
        __syncthreads();
    }
    if (t < nb) bsums[t] = s[t] - v;         // exclusive
}

// finalize offsets; convert padded counter slots into scatter cursors;
// emit compact degree + dinv; fill csr padding with sentinel zero-row.
__global__ void k_scan3(int* __restrict__ offs, const int* __restrict__ bsums,
                        int* __restrict__ deg_p,   // in: counts, out: cursors
                        int* __restrict__ deg_c, float* __restrict__ dinv,
                        int* __restrict__ csr) {
    int gi = blockIdx.x * 256 + threadIdx.x;
    if (gi >= N_NODES) return;
    int off = offs[gi] + bsums[blockIdx.x];
    offs[gi] = off;
    int d = deg_p[gi * PAD];
    deg_p[gi * PAD] = off;                   // becomes the scatter cursor
    deg_c[gi] = d;
    dinv[gi] = (d > 0) ? rsqrtf((float)d) : 0.0f;
    int pd = (d + 7) & ~7;
    for (int j = d; j < pd; j++) csr[off + j] = N_NODES;   // sentinel -> zero row
}

// one edge per thread; cursor padded (64B/counter)
__global__ void k_scatter(const int* __restrict__ row, const int* __restrict__ col,
                          int* __restrict__ cursor_p, int* __restrict__ csr) {
    int e = blockIdx.x * blockDim.x + threadIdx.x;
    if (e >= N_EDGES) return;
    int pos = atomicAdd(&cursor_p[col[e] * PAD], 1);
    csr[pos] = row[e];
}

// ---------------- tall-skinny GEMM: H[n] = dinv[n] * (X[n,:] @ W) ----------------
// block = 256 threads = 4 waves; each wave does 8 nodes, lane = output channel.

template <int CIN>
__global__ __launch_bounds__(256) void k_gemm(const float* __restrict__ X,
                                              const float* __restrict__ W,
                                              const float* __restrict__ dinv,
                                              float* __restrict__ H) {
    constexpr int STR = CIN + 4;               // pad to break bank alias
    __shared__ float sW[64 * STR];             // W transposed: sW[c*STR + k]
    __shared__ float sX[32 * STR];             // 32 nodes of X
    const int t = threadIdx.x;

    for (int idx = t; idx < CIN * 64; idx += 256) {
        int k = idx >> 6, c = idx & 63;
        sW[c * STR + k] = W[idx];
    }
    const int nb = blockIdx.x * 32;
    for (int f4 = t; f4 < 32 * CIN / 4; f4 += 256) {
        int f = f4 * 4;
        int nl = f / CIN, kk = f % CIN;
        const float4 v = *reinterpret_cast<const float4*>(X + (size_t)(nb + nl) * CIN + kk);
        *reinterpret_cast<float4*>(&sX[nl * STR + kk]) = v;
    }
    __syncthreads();

    const int wave = t >> 6, lane = t & 63;
    const int n0 = wave * 8;
    float acc[8] = {0.f,0.f,0.f,0.f,0.f,0.f,0.f,0.f};
    for (int kq = 0; kq < CIN; kq += 4) {
        const float4 w4 = *reinterpret_cast<const float4*>(&sW[lane * STR + kq]);
        #pragma unroll
        for (int n = 0; n < 8; n++) {
            const float4 x4 = *reinterpret_cast<const float4*>(&sX[(n0 + n) * STR + kq]);
            acc[n] += w4.x * x4.x + w4.y * x4.y + w4.z * x4.z + w4.w * x4.w;
        }
    }
    #pragma unroll
    for (int n = 0; n < 8; n++) {
        H[(size_t)(nb + n0 + n) * 64 + lane] = acc[n] * dinv[nb + n0 + n];
    }
}

// ---------------- propagation: Hout[v] = dinv[v] * sum_e Hin[row_e] + bias ----------------
// one wave per node, lane = channel; segments padded to x8 with sentinel
// zero-row => branch-free 8-wide unroll, 8 independent gathers in flight.

__global__ __launch_bounds__(256) void k_prop(const float* __restrict__ Hin,
                                              const int* __restrict__ csr,
                                              const int* __restrict__ offs,
                                              const int* __restrict__ deg_c,
                                              const float* __restrict__ dinv,
                                              const float* __restrict__ bias,
                                              float* __restrict__ Hout) {
    const int wave = threadIdx.x >> 6, lane = threadIdx.x & 63;
    const int v = blockIdx.x * 4 + wave;
    if (v >= N_NODES) return;
    const int start = offs[v];                 // multiple of 8 -> 32B aligned
    const int cntp = (deg_c[v] + 7) & ~7;
    const int* ep = csr + start;
    float acc = 0.f;
    for (int j = 0; j < cntp; j += 8) {
        const int4 q0 = *reinterpret_cast<const int4*>(ep + j);
        const int4 q1 = *reinterpret_cast<const int4*>(ep + j + 4);
        float s0 = Hin[(size_t)q0.x * 64 + lane];
        float s1 = Hin[(size_t)q0.y * 64 + lane];
        float s2 = Hin[(size_t)q0.z * 64 + lane];
        float s3 = Hin[(size_t)q0.w * 64 + lane];
        float s4 = Hin[(size_t)q1.x * 64 + lane];
        float s5 = Hin[(size_t)q1.y * 64 + lane];
        float s6 = Hin[(size_t)q1.z * 64 + lane];
        float s7 = Hin[(size_t)q1.w * 64 + lane];
        acc += ((s0 + s1) + (s2 + s3)) + ((s4 + s5) + (s6 + s7));
    }
    Hout[(size_t)v * 64 + lane] = dinv[v] * acc + bias[lane];
}

// ---------------- pooling ----------------

__global__ void k_pool(const float* __restrict__ H, const int* __restrict__ batch,
                       float* __restrict__ gsums) {
    const int gw = (blockIdx.x * blockDim.x + threadIdx.x) >> 6;
    const int lane = threadIdx.x & 63;
    const int nwaves = (gridDim.x * blockDim.x) >> 6;
    const int chunk = (N_NODES + nwaves - 1) / nwaves;
    int v0 = gw * chunk;
    int v1 = min(v0 + chunk, N_NODES);
    if (v0 >= v1) return;
    float acc = 0.f;
    int cur = batch[v0];
    for (int v = v0; v < v1; v++) {
        int g = batch[v];
        if (g != cur) {
            atomicAdd(&gsums[cur * 64 + lane], acc);
            acc = 0.f; cur = g;
        }
        acc += H[(size_t)v * 64 + lane];
    }
    atomicAdd(&gsums[cur * 64 + lane], acc);
}

__global__ void k_final(const float* __restrict__ gsums, const int* __restrict__ batch,
                        const float* __restrict__ Wl, const float* __restrict__ bl,
                        float* __restrict__ out) {
    __shared__ int scnt[128];
    int t = threadIdx.x;
    int lo = 0, hi = N_NODES;
    while (lo < hi) { int mid = (lo + hi) >> 1; if (batch[mid] < t) lo = mid + 1; else hi = mid; }
    int a = lo;
    lo = 0; hi = N_NODES;
    while (lo < hi) { int mid = (lo + hi) >> 1; if (batch[mid] < t + 1) lo = mid + 1; else hi = mid; }
    scnt[t] = lo - a;
    __syncthreads();
    for (int off = 64; off > 0; off >>= 1) {
        if (t < off) scnt[t] = max(scnt[t], scnt[t + off]);
        __syncthreads();
    }
    float nmax = (float)scnt[0];
    float s = 0.f;
    for (int c = 0; c < 64; c++) s += gsums[(size_t)t * 64 + c] * Wl[c];
    out[t] = s / nmax + bl[0];
}

// ---------------- launch ----------------

extern "C" void kernel_launch(void* const* d_in, const int* in_sizes, int n_in,
                              void* d_out, int out_size, void* d_ws, size_t ws_size,
                              hipStream_t stream) {
    const float* x    = (const float*)d_in[0];
    const int*   ei   = (const int*)d_in[1];     // [2, E] int32
    const int*   batch= (const int*)d_in[2];
    const float* W1 = (const float*)d_in[3];  const float* b1 = (const float*)d_in[4];
    const float* W2 = (const float*)d_in[5];  const float* b2 = (const float*)d_in[6];
    const float* W3 = (const float*)d_in[7];  const float* b3 = (const float*)d_in[8];
    const float* W4 = (const float*)d_in[9];  const float* b4 = (const float*)d_in[10];
    const float* Wl = (const float*)d_in[11]; const float* bl = (const float*)d_in[12];
    float* out = (float*)d_out;

    const int* row = ei;
    const int* col = ei + N_EDGES;

    // workspace layout (256B aligned blocks)
    char* ws = (char*)d_ws;
    size_t off = 0;
    auto alloc = [&](size_t bytes) {
        void* p = ws + off;
        off = (off + bytes + 255) & ~(size_t)255;
        return p;
    };
    int*   deg_p   = (int*)alloc((size_t)N_NODES * PAD * 4); // padded counters/cursors
    int*   offs    = (int*)alloc(N_NODES * 4);
    int*   deg_c   = (int*)alloc(N_NODES * 4);
    float* dinv    = (float*)alloc(N_NODES * 4);
    int*   bsums   = (int*)alloc(512 * 4);
    int*   csr     = (int*)alloc(((size_t)N_EDGES + 8 * N_NODES) * 4);  // padded
    float* h_a     = (float*)alloc((size_t)(N_NODES + 1) * 64 * 4);     // +1 zero row
    float* h_b     = (float*)alloc((size_t)(N_NODES + 1) * 64 * 4);
    float* gsums   = (float*)alloc(N_GRAPHS * 64 * 4);

    const int SCAN_BLOCKS = (N_NODES + 255) / 256;   // 391

    hipMemsetAsync(deg_p, 0, (size_t)N_NODES * PAD * 4, stream);
    hipMemsetAsync(gsums, 0, N_GRAPHS * 64 * 4, stream);
    hipMemsetAsync(h_a + (size_t)N_NODES * 64, 0, 64 * 4, stream);
    hipMemsetAsync(h_b + (size_t)N_NODES * 64, 0, 64 * 4, stream);

    k_count<<<(N_EDGES + 255) / 256, 256, 0, stream>>>(col, deg_p);
    k_scan1<<<SCAN_BLOCKS, 256, 0, stream>>>(deg_p, offs, bsums);
    k_scan2<<<1, 512, 0, stream>>>(bsums, SCAN_BLOCKS);
    k_scan3<<<SCAN_BLOCKS, 256, 0, stream>>>(offs, bsums, deg_p, deg_c, dinv, csr);
    k_scatter<<<(N_EDGES + 255) / 256, 256, 0, stream>>>(row, col, deg_p, csr);

    // layer 1: h_a = dinv * (x @ W1) ; h_b = dinv * prop(h_a) + b1
    k_gemm<128><<<N_NODES / 32, 256, 0, stream>>>(x, W1, dinv, h_a);
    k_prop<<<N_NODES / 4, 256, 0, stream>>>(h_a, csr, offs, deg_c, dinv, b1, h_b);
    // layer 2
    k_gemm<64><<<N_NODES / 32, 256, 0, stream>>>(h_b, W2, dinv, h_a);
    k_prop<<<N_NODES / 4, 256, 0, stream>>>(h_a, csr, offs, deg_c, dinv, b2, h_b);
    // layer 3
    k_gemm<64><<<N_NODES / 32, 256, 0, stream>>>(h_b, W3, dinv, h_a);
    k_prop<<<N_NODES / 4, 256, 0, stream>>>(h_a, csr, offs, deg_c, dinv, b3, h_b);
    // layer 4
    k_gemm<64><<<N_NODES / 32, 256, 0, stream>>>(h_b, W4, dinv, h_a);
    k_prop<<<N_NODES / 4, 256, 0, stream>>>(h_a, csr, offs, deg_c, dinv, b4, h_b);

    // pooling + readout
    k_pool<<<98, 256, 0, stream>>>(h_b, batch, gsums);
    k_final<<<1, 128, 0, stream>>>(gsums, batch, Wl, bl, out);
}

// Round 5
// 608.434 us; speedup vs baseline: 1.3102x; 1.2932x over previous
//
#include <hip/hip_runtime.h>
#include <hip/hip_bf16.h>

// Problem constants (match reference)
#define N_NODES 100000
#define N_EDGES 1600000
#define N_GRAPHS 128

// Counting-sort CSR build parameters
#define BSH 9                 // bucket = col >> 9
#define BNODES 512            // nodes per bucket
#define NB 196                // ceil(100000 / 512)
#define CAP 12288             // static per-bucket csr/record capacity (elems)
#define BLK 512               // histogram blocks
#define EPB (N_EDGES / BLK)   // 3125 edges per block (exact)
#define RECMAX 10240          // max records per bucket held in LDS (mean 8163, +23 sigma)

// ---------------- CSR build (no global atomics) ----------------

// per-block bucket histogram (LDS atomics only)
__global__ __launch_bounds__(256) void k_hist(const int* __restrict__ col,
                                              int* __restrict__ hist_t) {
    __shared__ int h[NB];
    const int t = threadIdx.x, b = blockIdx.x;
    for (int i = t; i < NB; i += 256) h[i] = 0;
    __syncthreads();
    const int e0 = b * EPB;
    for (int i = t; i < EPB; i += 256) atomicAdd(&h[col[e0 + i] >> BSH], 1);
    __syncthreads();
    for (int i = t; i < NB; i += 256) hist_t[i * BLK + b] = h[i];
}

// per-bucket scan over the 512 block counts -> per-(bucket,block) cursors.
// Bucket bases are static (bin * CAP), so no global scan is needed.
__global__ __launch_bounds__(512) void k_cursors(const int* __restrict__ hist_t,
                                                 int* __restrict__ cursors,
                                                 int* __restrict__ bcnt) {
    __shared__ int s[BLK];
    const int t = threadIdx.x, bin = blockIdx.x;
    const int v = hist_t[bin * BLK + t];
    s[t] = v; __syncthreads();
    for (int off = 1; off < BLK; off <<= 1) {
        int a = (t >= off) ? s[t - off] : 0;
        __syncthreads(); s[t] += a; __syncthreads();
    }
    cursors[bin * BLK + t] = bin * CAP + s[t] - v;   // exclusive + static base
    if (t == BLK - 1) bcnt[bin] = s[t];
}

// place packed records into bucket-contiguous regions via LDS cursors.
// Consecutive positions in a (bucket,block) come from the same block -> merge.
__global__ __launch_bounds__(256) void k_mid(const int* __restrict__ row,
                                             const int* __restrict__ col,
                                             const int* __restrict__ cursors,
                                             int* __restrict__ bedges) {
    __shared__ int cur[NB];
    const int t = threadIdx.x, b = blockIdx.x;
    for (int i = t; i < NB; i += 256) cur[i] = cursors[i * BLK + b];
    __syncthreads();
    const int e0 = b * EPB;
    for (int i = t; i < EPB; i += 256) {
        const int c = col[e0 + i];
        const int r = row[e0 + i];
        const int pos = atomicAdd(&cur[c >> BSH], 1);
        bedges[pos] = r | ((c & (BNODES - 1)) << 17);   // row<2^17, lcol 9 bits
    }
}

// one workgroup per bucket: build the final padded CSR segment in a contiguous
// window, plus offs/deg/dinv. csr aliases bedges (records LDS-resident before
// any csr write; regions are per-bucket disjoint).
__global__ __launch_bounds__(512) void k_build(const int* __restrict__ bedges,
                                               const int* __restrict__ bcnt,
                                               int* __restrict__ csr,
                                               int* __restrict__ offs,
                                               int* __restrict__ deg_c,
                                               float* __restrict__ dinv) {
    __shared__ int rec[RECMAX];
    __shared__ int deg[BNODES];
    __shared__ int offx[BNODES];
    __shared__ int cur[BNODES];
    const int t = threadIdx.x, bin = blockIdx.x;
    const int base = bin * CAP;
    const int cnt = bcnt[bin];
    const int vb = bin << BSH;
    const int nn = min(BNODES, N_NODES - vb);
    for (int i = t; i < cnt; i += 512) rec[i] = bedges[base + i];
    deg[t] = 0;
    __syncthreads();                 // all record loads done before any csr write
    for (int i = t; i < cnt; i += 512) atomicAdd(&deg[(rec[i] >> 17) & (BNODES - 1)], 1);
    __syncthreads();
    const int d = (t < nn) ? deg[t] : 0;
    const int pd = (d + 7) & ~7;     // pad each segment to x8
    offx[t] = pd; __syncthreads();
    for (int off = 1; off < BNODES; off <<= 1) {
        int a = (t >= off) ? offx[t - off] : 0;
        __syncthreads(); offx[t] += a; __syncthreads();
    }
    const int myoff = offx[t] - pd;  // exclusive
    cur[t] = myoff;
    if (t < nn) {
        offs[vb + t] = base + myoff;
        deg_c[vb + t] = d;
        dinv[vb + t] = (d > 0) ? rsqrtf((float)d) : 0.0f;
        for (int j = d; j < pd; j++) csr[base + myoff + j] = N_NODES;  // sentinel
    }
    __syncthreads();
    for (int i = t; i < cnt; i += 512) {
        const int r = rec[i];
        const int pos = atomicAdd(&cur[(r >> 17) & (BNODES - 1)], 1);
        csr[base + pos] = r & 0x1FFFF;
    }
}

// ---------------- tall-skinny GEMM: H[n] = dinv[n] * (X[n,:] @ W) ----------------
// block = 256 threads = 4 waves; each wave does 8 nodes, lane = output channel.

template <int CIN>
__global__ __launch_bounds__(256) void k_gemm(const float* __restrict__ X,
                                              const float* __restrict__ W,
                                              const float* __restrict__ dinv,
                                              float* __restrict__ H) {
    constexpr int STR = CIN + 4;               // pad to break bank alias
    __shared__ float sW[64 * STR];             // W transposed: sW[c*STR + k]
    __shared__ float sX[32 * STR];             // 32 nodes of X
    const int t = threadIdx.x;

    for (int idx = t; idx < CIN * 64; idx += 256) {
        int k = idx >> 6, c = idx & 63;
        sW[c * STR + k] = W[idx];
    }
    const int nb = blockIdx.x * 32;
    for (int f4 = t; f4 < 32 * CIN / 4; f4 += 256) {
        int f = f4 * 4;
        int nl = f / CIN, kk = f % CIN;
        const float4 v = *reinterpret_cast<const float4*>(X + (size_t)(nb + nl) * CIN + kk);
        *reinterpret_cast<float4*>(&sX[nl * STR + kk]) = v;
    }
    __syncthreads();

    const int wave = t >> 6, lane = t & 63;
    const int n0 = wave * 8;
    float acc[8] = {0.f,0.f,0.f,0.f,0.f,0.f,0.f,0.f};
    for (int kq = 0; kq < CIN; kq += 4) {
        const float4 w4 = *reinterpret_cast<const float4*>(&sW[lane * STR + kq]);
        #pragma unroll
        for (int n = 0; n < 8; n++) {
            const float4 x4 = *reinterpret_cast<const float4*>(&sX[(n0 + n) * STR + kq]);
            acc[n] += w4.x * x4.x + w4.y * x4.y + w4.z * x4.z + w4.w * x4.w;
        }
    }
    #pragma unroll
    for (int n = 0; n < 8; n++) {
        H[(size_t)(nb + n0 + n) * 64 + lane] = acc[n] * dinv[nb + n0 + n];
    }
}

// ---------------- propagation: Hout[v] = dinv[v] * sum_e Hin[row_e] + bias ----------------
// one wave per node, lane = channel; segments padded to x8 with sentinel
// zero-row => branch-free 8-wide unroll, 8 independent gathers in flight.

__global__ __launch_bounds__(256) void k_prop(const float* __restrict__ Hin,
                                              const int* __restrict__ csr,
                                              const int* __restrict__ offs,
                                              const int* __restrict__ deg_c,
                                              const float* __restrict__ dinv,
                                              const float* __restrict__ bias,
                                              float* __restrict__ Hout) {
    const int wave = threadIdx.x >> 6, lane = threadIdx.x & 63;
    const int v = blockIdx.x * 4 + wave;
    if (v >= N_NODES) return;
    const int start = offs[v];                 // multiple of 8 -> 32B aligned
    const int cntp = (deg_c[v] + 7) & ~7;
    const int* ep = csr + start;
    float acc = 0.f;
    for (int j = 0; j < cntp; j += 8) {
        const int4 q0 = *reinterpret_cast<const int4*>(ep + j);
        const int4 q1 = *reinterpret_cast<const int4*>(ep + j + 4);
        float s0 = Hin[(size_t)q0.x * 64 + lane];
        float s1 = Hin[(size_t)q0.y * 64 + lane];
        float s2 = Hin[(size_t)q0.z * 64 + lane];
        float s3 = Hin[(size_t)q0.w * 64 + lane];
        float s4 = Hin[(size_t)q1.x * 64 + lane];
        float s5 = Hin[(size_t)q1.y * 64 + lane];
        float s6 = Hin[(size_t)q1.z * 64 + lane];
        float s7 = Hin[(size_t)q1.w * 64 + lane];
        acc += ((s0 + s1) + (s2 + s3)) + ((s4 + s5) + (s6 + s7));
    }
    Hout[(size_t)v * 64 + lane] = dinv[v] * acc + bias[lane];
}

// ---------------- pooling ----------------

__global__ void k_pool(const float* __restrict__ H, const int* __restrict__ batch,
                       float* __restrict__ gsums) {
    const int gw = (blockIdx.x * blockDim.x + threadIdx.x) >> 6;
    const int lane = threadIdx.x & 63;
    const int nwaves = (gridDim.x * blockDim.x) >> 6;
    const int chunk = (N_NODES + nwaves - 1) / nwaves;
    int v0 = gw * chunk;
    int v1 = min(v0 + chunk, N_NODES);
    if (v0 >= v1) return;
    float acc = 0.f;
    int cur = batch[v0];
    for (int v = v0; v < v1; v++) {
        int g = batch[v];
        if (g != cur) {
            atomicAdd(&gsums[cur * 64 + lane], acc);
            acc = 0.f; cur = g;
        }
        acc += H[(size_t)v * 64 + lane];
    }
    atomicAdd(&gsums[cur * 64 + lane], acc);
}

__global__ void k_final(const float* __restrict__ gsums, const int* __restrict__ batch,
                        const float* __restrict__ Wl, const float* __restrict__ bl,
                        float* __restrict__ out) {
    __shared__ int scnt[128];
    int t = threadIdx.x;
    int lo = 0, hi = N_NODES;
    while (lo < hi) { int mid = (lo + hi) >> 1; if (batch[mid] < t) lo = mid + 1; else hi = mid; }
    int a = lo;
    lo = 0; hi = N_NODES;
    while (lo < hi) { int mid = (lo + hi) >> 1; if (batch[mid] < t + 1) lo = mid + 1; else hi = mid; }
    scnt[t] = lo - a;
    __syncthreads();
    for (int off = 64; off > 0; off >>= 1) {
        if (t < off) scnt[t] = max(scnt[t], scnt[t + off]);
        __syncthreads();
    }
    float nmax = (float)scnt[0];
    float s = 0.f;
    for (int c = 0; c < 64; c++) s += gsums[(size_t)t * 64 + c] * Wl[c];
    out[t] = s / nmax + bl[0];
}

// ---------------- launch ----------------

extern "C" void kernel_launch(void* const* d_in, const int* in_sizes, int n_in,
                              void* d_out, int out_size, void* d_ws, size_t ws_size,
                              hipStream_t stream) {
    const float* x    = (const float*)d_in[0];
    const int*   ei   = (const int*)d_in[1];     // [2, E] int32
    const int*   batch= (const int*)d_in[2];
    const float* W1 = (const float*)d_in[3];  const float* b1 = (const float*)d_in[4];
    const float* W2 = (const float*)d_in[5];  const float* b2 = (const float*)d_in[6];
    const float* W3 = (const float*)d_in[7];  const float* b3 = (const float*)d_in[8];
    const float* W4 = (const float*)d_in[9];  const float* b4 = (const float*)d_in[10];
    const float* Wl = (const float*)d_in[11]; const float* bl = (const float*)d_in[12];
    float* out = (float*)d_out;

    const int* row = ei;
    const int* col = ei + N_EDGES;

    // workspace layout (256B aligned blocks)
    char* ws = (char*)d_ws;
    size_t off = 0;
    auto alloc = [&](size_t bytes) {
        void* p = ws + off;
        off = (off + bytes + 255) & ~(size_t)255;
        return p;
    };
    int*   hist_t  = (int*)alloc((size_t)NB * BLK * 4);
    int*   cursors = (int*)alloc((size_t)NB * BLK * 4);
    int*   bcnt    = (int*)alloc(NB * 4);
    int*   bedges  = (int*)alloc((size_t)NB * CAP * 4);   // aliased by csr
    int*   csr     = bedges;                              // in-place rebuild (safe)
    int*   offs    = (int*)alloc(N_NODES * 4);
    int*   deg_c   = (int*)alloc(N_NODES * 4);
    float* dinv    = (float*)alloc(N_NODES * 4);
    float* h_a     = (float*)alloc((size_t)(N_NODES + 1) * 64 * 4);   // +1 zero row
    float* h_b     = (float*)alloc((size_t)(N_NODES + 1) * 64 * 4);
    float* gsums   = (float*)alloc(N_GRAPHS * 64 * 4);

    hipMemsetAsync(gsums, 0, N_GRAPHS * 64 * 4, stream);
    hipMemsetAsync(h_a + (size_t)N_NODES * 64, 0, 64 * 4, stream);
    hipMemsetAsync(h_b + (size_t)N_NODES * 64, 0, 64 * 4, stream);

    // CSR build: histogram -> cursors -> bucket scatter -> per-bucket build
    k_hist<<<BLK, 256, 0, stream>>>(col, hist_t);
    k_cursors<<<NB, 512, 0, stream>>>(hist_t, cursors, bcnt);
    k_mid<<<BLK, 256, 0, stream>>>(row, col, cursors, bedges);
    k_build<<<NB, 512, 0, stream>>>(bedges, bcnt, csr, offs, deg_c, dinv);

    // layer 1: h_a = dinv * (x @ W1) ; h_b = dinv * prop(h_a) + b1
    k_gemm<128><<<N_NODES / 32, 256, 0, stream>>>(x, W1, dinv, h_a);
    k_prop<<<N_NODES / 4, 256, 0, stream>>>(h_a, csr, offs, deg_c, dinv, b1, h_b);
    // layer 2
    k_gemm<64><<<N_NODES / 32, 256, 0, stream>>>(h_b, W2, dinv, h_a);
    k_prop<<<N_NODES / 4, 256, 0, stream>>>(h_a, csr, offs, deg_c, dinv, b2, h_b);
    // layer 3
    k_gemm<64><<<N_NODES / 32, 256, 0, stream>>>(h_b, W3, dinv, h_a);
    k_prop<<<N_NODES / 4, 256, 0, stream>>>(h_a, csr, offs, deg_c, dinv, b3, h_b);
    // layer 4
    k_gemm<64><<<N_NODES / 32, 256, 0, stream>>>(h_b, W4, dinv, h_a);
    k_prop<<<N_NODES / 4, 256, 0, stream>>>(h_a, csr, offs, deg_c, dinv, b4, h_b);

    // pooling + readout
    k_pool<<<98, 256, 0, stream>>>(h_b, batch, gsums);
    k_final<<<1, 128, 0, stream>>>(gsums, batch, Wl, bl, out);
}

// Round 6
// 544.083 us; speedup vs baseline: 1.4651x; 1.1183x over previous
//
#include <hip/hip_runtime.h>
#include <hip/hip_bf16.h>

// Problem constants (match reference)
#define N_NODES 100000
#define N_EDGES 1600000
#define N_GRAPHS 128

// Counting-sort CSR build parameters
#define BSH 9                 // bucket = col >> 9
#define BNODES 512            // nodes per bucket
#define NB 196                // ceil(100000 / 512)
#define CAP 12288             // static per-bucket csr/record capacity (elems)
#define BLK 512               // histogram blocks
#define EPB (N_EDGES / BLK)   // 3125 edges per block (exact)
#define RECMAX 10240          // max records per bucket held in LDS (mean 8163, +23 sigma)

#define SPLIT 4               // pooling blocks per graph

// ---------------- CSR build (no global atomics) ----------------

// per-block bucket histogram (LDS atomics only)
__global__ __launch_bounds__(256) void k_hist(const int* __restrict__ col,
                                              int* __restrict__ hist_t) {
    __shared__ int h[NB];
    const int t = threadIdx.x, b = blockIdx.x;
    for (int i = t; i < NB; i += 256) h[i] = 0;
    __syncthreads();
    const int e0 = b * EPB;
    for (int i = t; i < EPB; i += 256) atomicAdd(&h[col[e0 + i] >> BSH], 1);
    __syncthreads();
    for (int i = t; i < NB; i += 256) hist_t[i * BLK + b] = h[i];
}

// per-bucket scan over the 512 block counts -> per-(bucket,block) cursors.
__global__ __launch_bounds__(512) void k_cursors(const int* __restrict__ hist_t,
                                                 int* __restrict__ cursors,
                                                 int* __restrict__ bcnt) {
    __shared__ int s[BLK];
    const int t = threadIdx.x, bin = blockIdx.x;
    const int v = hist_t[bin * BLK + t];
    s[t] = v; __syncthreads();
    for (int off = 1; off < BLK; off <<= 1) {
        int a = (t >= off) ? s[t - off] : 0;
        __syncthreads(); s[t] += a; __syncthreads();
    }
    cursors[bin * BLK + t] = bin * CAP + s[t] - v;   // exclusive + static base
    if (t == BLK - 1) bcnt[bin] = s[t];
}

// place packed records into bucket-contiguous regions via LDS cursors.
__global__ __launch_bounds__(256) void k_mid(const int* __restrict__ row,
                                             const int* __restrict__ col,
                                             const int* __restrict__ cursors,
                                             int* __restrict__ bedges) {
    __shared__ int cur[NB];
    const int t = threadIdx.x, b = blockIdx.x;
    for (int i = t; i < NB; i += 256) cur[i] = cursors[i * BLK + b];
    __syncthreads();
    const int e0 = b * EPB;
    for (int i = t; i < EPB; i += 256) {
        const int c = col[e0 + i];
        const int r = row[e0 + i];
        const int pos = atomicAdd(&cur[c >> BSH], 1);
        bedges[pos] = r | ((c & (BNODES - 1)) << 17);   // row<2^17, lcol 9 bits
    }
}

// one workgroup per bucket: build the final padded CSR segment in a contiguous
// window, plus offs/deg/dinv. csr aliases bedges (records LDS-resident before
// any csr write; regions are per-bucket disjoint).
__global__ __launch_bounds__(512) void k_build(const int* __restrict__ bedges,
                                               const int* __restrict__ bcnt,
                                               int* __restrict__ csr,
                                               int* __restrict__ offs,
                                               int* __restrict__ deg_c,
                                               float* __restrict__ dinv) {
    __shared__ int rec[RECMAX];
    __shared__ int deg[BNODES];
    __shared__ int offx[BNODES];
    __shared__ int cur[BNODES];
    const int t = threadIdx.x, bin = blockIdx.x;
    const int base = bin * CAP;
    const int cnt = bcnt[bin];
    const int vb = bin << BSH;
    const int nn = min(BNODES, N_NODES - vb);
    for (int i = t; i < cnt; i += 512) rec[i] = bedges[base + i];
    deg[t] = 0;
    __syncthreads();                 // all record loads done before any csr write
    for (int i = t; i < cnt; i += 512) atomicAdd(&deg[(rec[i] >> 17) & (BNODES - 1)], 1);
    __syncthreads();
    const int d = (t < nn) ? deg[t] : 0;
    const int pd = (d + 7) & ~7;     // pad each segment to x8
    offx[t] = pd; __syncthreads();
    for (int off = 1; off < BNODES; off <<= 1) {
        int a = (t >= off) ? offx[t - off] : 0;
        __syncthreads(); offx[t] += a; __syncthreads();
    }
    const int myoff = offx[t] - pd;  // exclusive
    cur[t] = myoff;
    if (t < nn) {
        offs[vb + t] = base + myoff;
        deg_c[vb + t] = d;
        dinv[vb + t] = (d > 0) ? rsqrtf((float)d) : 0.0f;
        for (int j = d; j < pd; j++) csr[base + myoff + j] = N_NODES;  // sentinel
    }
    __syncthreads();
    for (int i = t; i < cnt; i += 512) {
        const int r = rec[i];
        const int pos = atomicAdd(&cur[(r >> 17) & (BNODES - 1)], 1);
        csr[base + pos] = r & 0x1FFFF;
    }
}

// ---------------- tall-skinny GEMM: H[n] = dinv[n] * (X[n,:] @ W) ----------------

template <int CIN>
__global__ __launch_bounds__(256) void k_gemm(const float* __restrict__ X,
                                              const float* __restrict__ W,
                                              const float* __restrict__ dinv,
                                              float* __restrict__ H) {
    constexpr int STR = CIN + 4;               // pad to break bank alias
    __shared__ float sW[64 * STR];             // W transposed: sW[c*STR + k]
    __shared__ float sX[32 * STR];             // 32 nodes of X
    const int t = threadIdx.x;

    for (int idx = t; idx < CIN * 64; idx += 256) {
        int k = idx >> 6, c = idx & 63;
        sW[c * STR + k] = W[idx];
    }
    const int nb = blockIdx.x * 32;
    for (int f4 = t; f4 < 32 * CIN / 4; f4 += 256) {
        int f = f4 * 4;
        int nl = f / CIN, kk = f % CIN;
        const float4 v = *reinterpret_cast<const float4*>(X + (size_t)(nb + nl) * CIN + kk);
        *reinterpret_cast<float4*>(&sX[nl * STR + kk]) = v;
    }
    __syncthreads();

    const int wave = t >> 6, lane = t & 63;
    const int n0 = wave * 8;
    float acc[8] = {0.f,0.f,0.f,0.f,0.f,0.f,0.f,0.f};
    for (int kq = 0; kq < CIN; kq += 4) {
        const float4 w4 = *reinterpret_cast<const float4*>(&sW[lane * STR + kq]);
        #pragma unroll
        for (int n = 0; n < 8; n++) {
            const float4 x4 = *reinterpret_cast<const float4*>(&sX[(n0 + n) * STR + kq]);
            acc[n] += w4.x * x4.x + w4.y * x4.y + w4.z * x4.z + w4.w * x4.w;
        }
    }
    #pragma unroll
    for (int n = 0; n < 8; n++) {
        H[(size_t)(nb + n0 + n) * 64 + lane] = acc[n] * dinv[nb + n0 + n];
    }
}

// ---------------- propagation: Hout[v] = dinv[v] * sum_e Hin[row_e] + bias ----------------

__global__ __launch_bounds__(256) void k_prop(const float* __restrict__ Hin,
                                              const int* __restrict__ csr,
                                              const int* __restrict__ offs,
                                              const int* __restrict__ deg_c,
                                              const float* __restrict__ dinv,
                                              const float* __restrict__ bias,
                                              float* __restrict__ Hout) {
    const int wave = threadIdx.x >> 6, lane = threadIdx.x & 63;
    const int v = blockIdx.x * 4 + wave;
    if (v >= N_NODES) return;
    const int start = offs[v];                 // multiple of 8 -> 32B aligned
    const int cntp = (deg_c[v] + 7) & ~7;
    const int* ep = csr + start;
    float acc = 0.f;
    for (int j = 0; j < cntp; j += 8) {
        const int4 q0 = *reinterpret_cast<const int4*>(ep + j);
        const int4 q1 = *reinterpret_cast<const int4*>(ep + j + 4);
        float s0 = Hin[(size_t)q0.x * 64 + lane];
        float s1 = Hin[(size_t)q0.y * 64 + lane];
        float s2 = Hin[(size_t)q0.z * 64 + lane];
        float s3 = Hin[(size_t)q0.w * 64 + lane];
        float s4 = Hin[(size_t)q1.x * 64 + lane];
        float s5 = Hin[(size_t)q1.y * 64 + lane];
        float s6 = Hin[(size_t)q1.z * 64 + lane];
        float s7 = Hin[(size_t)q1.w * 64 + lane];
        acc += ((s0 + s1) + (s2 + s3)) + ((s4 + s5) + (s6 + s7));
    }
    Hout[(size_t)v * 64 + lane] = dinv[v] * acc + bias[lane];
}

// ---------------- pooling: one (graph, split) block; atomic-free partials ----------------

__global__ __launch_bounds__(256) void k_pool(const float* __restrict__ H,
                                              const int* __restrict__ batch,
                                              float* __restrict__ partial) {
    const int g = blockIdx.x >> 2;           // graph
    const int s = blockIdx.x & (SPLIT - 1);  // split
    // graph g node range [a, b) via binary search (batch sorted)
    int lo = 0, hi = N_NODES;
    while (lo < hi) { int m = (lo + hi) >> 1; if (batch[m] < g) lo = m + 1; else hi = m; }
    const int a = lo;
    lo = 0; hi = N_NODES;
    while (lo < hi) { int m = (lo + hi) >> 1; if (batch[m] < g + 1) lo = m + 1; else hi = m; }
    const int b = lo;

    const int wave = threadIdx.x >> 6, lane = threadIdx.x & 63;
    const int lane16 = s * 4 + wave;         // 0..15: stride position
    float ac0 = 0.f, ac1 = 0.f, ac2 = 0.f, ac3 = 0.f;
    int v = a + lane16;
    for (; v + 48 < b; v += 64) {            // 4 independent loads in flight
        ac0 += H[(size_t)v * 64 + lane];
        ac1 += H[(size_t)(v + 16) * 64 + lane];
        ac2 += H[(size_t)(v + 32) * 64 + lane];
        ac3 += H[(size_t)(v + 48) * 64 + lane];
    }
    for (; v < b; v += 16) ac0 += H[(size_t)v * 64 + lane];
    const float acc = (ac0 + ac1) + (ac2 + ac3);

    __shared__ float red[4][64];
    red[wave][lane] = acc;
    __syncthreads();
    if (wave == 0) {
        const float r = (red[0][lane] + red[1][lane]) + (red[2][lane] + red[3][lane]);
        partial[((size_t)s * N_GRAPHS + g) * 64 + lane] = r;
    }
}

__global__ void k_final(const float* __restrict__ partial, const int* __restrict__ batch,
                        const float* __restrict__ Wl, const float* __restrict__ bl,
                        float* __restrict__ out) {
    __shared__ int scnt[128];
    int t = threadIdx.x;
    int lo = 0, hi = N_NODES;
    while (lo < hi) { int mid = (lo + hi) >> 1; if (batch[mid] < t) lo = mid + 1; else hi = mid; }
    int a = lo;
    lo = 0; hi = N_NODES;
    while (lo < hi) { int mid = (lo + hi) >> 1; if (batch[mid] < t + 1) lo = mid + 1; else hi = mid; }
    scnt[t] = lo - a;
    __syncthreads();
    for (int off = 64; off > 0; off >>= 1) {
        if (t < off) scnt[t] = max(scnt[t], scnt[t + off]);
        __syncthreads();
    }
    const float nmax = (float)scnt[0];
    float s = 0.f;
    for (int c = 0; c < 64; c++) {
        float g = 0.f;
        #pragma unroll
        for (int p = 0; p < SPLIT; p++)
            g += partial[((size_t)p * N_GRAPHS + t) * 64 + c];
        s += g * Wl[c];
    }
    out[t] = s / nmax + bl[0];
}

// ---------------- launch ----------------

extern "C" void kernel_launch(void* const* d_in, const int* in_sizes, int n_in,
                              void* d_out, int out_size, void* d_ws, size_t ws_size,
                              hipStream_t stream) {
    const float* x    = (const float*)d_in[0];
    const int*   ei   = (const int*)d_in[1];     // [2, E] int32
    const int*   batch= (const int*)d_in[2];
    const float* W1 = (const float*)d_in[3];  const float* b1 = (const float*)d_in[4];
    const float* W2 = (const float*)d_in[5];  const float* b2 = (const float*)d_in[6];
    const float* W3 = (const float*)d_in[7];  const float* b3 = (const float*)d_in[8];
    const float* W4 = (const float*)d_in[9];  const float* b4 = (const float*)d_in[10];
    const float* Wl = (const float*)d_in[11]; const float* bl = (const float*)d_in[12];
    float* out = (float*)d_out;

    const int* row = ei;
    const int* col = ei + N_EDGES;

    // workspace layout (256B aligned blocks)
    char* ws = (char*)d_ws;
    size_t off = 0;
    auto alloc = [&](size_t bytes) {
        void* p = ws + off;
        off = (off + bytes + 255) & ~(size_t)255;
        return p;
    };
    int*   hist_t  = (int*)alloc((size_t)NB * BLK * 4);
    int*   cursors = (int*)alloc((size_t)NB * BLK * 4);
    int*   bcnt    = (int*)alloc(NB * 4);
    int*   bedges  = (int*)alloc((size_t)NB * CAP * 4);   // aliased by csr
    int*   csr     = bedges;                              // in-place rebuild (safe)
    int*   offs    = (int*)alloc(N_NODES * 4);
    int*   deg_c   = (int*)alloc(N_NODES * 4);
    float* dinv    = (float*)alloc(N_NODES * 4);
    float* h_a     = (float*)alloc((size_t)(N_NODES + 1) * 64 * 4);   // +1 zero row
    float* h_b     = (float*)alloc((size_t)(N_NODES + 1) * 64 * 4);
    float* partial = (float*)alloc((size_t)SPLIT * N_GRAPHS * 64 * 4);

    hipMemsetAsync(h_a + (size_t)N_NODES * 64, 0, 64 * 4, stream);
    hipMemsetAsync(h_b + (size_t)N_NODES * 64, 0, 64 * 4, stream);

    // CSR build: histogram -> cursors -> bucket scatter -> per-bucket build
    k_hist<<<BLK, 256, 0, stream>>>(col, hist_t);
    k_cursors<<<NB, 512, 0, stream>>>(hist_t, cursors, bcnt);
    k_mid<<<BLK, 256, 0, stream>>>(row, col, cursors, bedges);
    k_build<<<NB, 512, 0, stream>>>(bedges, bcnt, csr, offs, deg_c, dinv);

    // layer 1: h_a = dinv * (x @ W1) ; h_b = dinv * prop(h_a) + b1
    k_gemm<128><<<N_NODES / 32, 256, 0, stream>>>(x, W1, dinv, h_a);
    k_prop<<<N_NODES / 4, 256, 0, stream>>>(h_a, csr, offs, deg_c, dinv, b1, h_b);
    // layer 2
    k_gemm<64><<<N_NODES / 32, 256, 0, stream>>>(h_b, W2, dinv, h_a);
    k_prop<<<N_NODES / 4, 256, 0, stream>>>(h_a, csr, offs, deg_c, dinv, b2, h_b);
    // layer 3
    k_gemm<64><<<N_NODES / 32, 256, 0, stream>>>(h_b, W3, dinv, h_a);
    k_prop<<<N_NODES / 4, 256, 0, stream>>>(h_a, csr, offs, deg_c, dinv, b3, h_b);
    // layer 4
    k_gemm<64><<<N_NODES / 32, 256, 0, stream>>>(h_b, W4, dinv, h_a);
    k_prop<<<N_NODES / 4, 256, 0, stream>>>(h_a, csr, offs, deg_c, dinv, b4, h_b);

    // pooling + readout (atomic-free)
    k_pool<<<N_GRAPHS * SPLIT, 256, 0, stream>>>(h_b, batch, partial);
    k_final<<<1, 128, 0, stream>>>(partial, batch, Wl, bl, out);
}

// Round 7
// 491.297 us; speedup vs baseline: 1.6225x; 1.1074x over previous
//
#include <hip/hip_runtime.h>
#include <hip/hip_bf16.h>

// Problem constants (match reference)
#define N_NODES 100000
#define N_EDGES 1600000
#define N_GRAPHS 128

// Counting-sort CSR build parameters
#define BSH 9                 // bucket = col >> 9
#define BNODES 512            // nodes per bucket
#define NB 196                // ceil(100000 / 512)
#define CAP 12288             // static per-bucket csr/record capacity (elems)
#define BLK 512               // histogram blocks
#define EPB (N_EDGES / BLK)   // 3125 edges per block (exact)
#define RECMAX 10240          // max records per bucket held in LDS

#define SPLIT 4               // pooling blocks per graph

// ---------------- CSR build (no global atomics) ----------------

__global__ __launch_bounds__(256) void k_hist(const int* __restrict__ col,
                                              int* __restrict__ hist_t) {
    __shared__ int h[NB];
    const int t = threadIdx.x, b = blockIdx.x;
    for (int i = t; i < NB; i += 256) h[i] = 0;
    __syncthreads();
    const int e0 = b * EPB;
    for (int i = t; i < EPB; i += 256) atomicAdd(&h[col[e0 + i] >> BSH], 1);
    __syncthreads();
    for (int i = t; i < NB; i += 256) hist_t[i * BLK + b] = h[i];
}

__global__ __launch_bounds__(512) void k_cursors(const int* __restrict__ hist_t,
                                                 int* __restrict__ cursors,
                                                 int* __restrict__ bcnt) {
    __shared__ int s[BLK];
    const int t = threadIdx.x, bin = blockIdx.x;
    const int v = hist_t[bin * BLK + t];
    s[t] = v; __syncthreads();
    for (int off = 1; off < BLK; off <<= 1) {
        int a = (t >= off) ? s[t - off] : 0;
        __syncthreads(); s[t] += a; __syncthreads();
    }
    cursors[bin * BLK + t] = bin * CAP + s[t] - v;   // exclusive + static base
    if (t == BLK - 1) bcnt[bin] = s[t];
}

__global__ __launch_bounds__(256) void k_mid(const int* __restrict__ row,
                                             const int* __restrict__ col,
                                             const int* __restrict__ cursors,
                                             int* __restrict__ bedges) {
    __shared__ int cur[NB];
    const int t = threadIdx.x, b = blockIdx.x;
    for (int i = t; i < NB; i += 256) cur[i] = cursors[i * BLK + b];
    __syncthreads();
    const int e0 = b * EPB;
    for (int i = t; i < EPB; i += 256) {
        const int c = col[e0 + i];
        const int r = row[e0 + i];
        const int pos = atomicAdd(&cur[c >> BSH], 1);
        bedges[pos] = r | ((c & (BNODES - 1)) << 17);   // row<2^17, lcol 9 bits
    }
}

__global__ __launch_bounds__(512) void k_build(const int* __restrict__ bedges,
                                               const int* __restrict__ bcnt,
                                               int* __restrict__ csr,
                                               int* __restrict__ offs,
                                               int* __restrict__ deg_c,
                                               float* __restrict__ dinv) {
    __shared__ int rec[RECMAX];
    __shared__ int deg[BNODES];
    __shared__ int offx[BNODES];
    __shared__ int cur[BNODES];
    const int t = threadIdx.x, bin = blockIdx.x;
    const int base = bin * CAP;
    const int cnt = bcnt[bin];
    const int vb = bin << BSH;
    const int nn = min(BNODES, N_NODES - vb);
    for (int i = t; i < cnt; i += 512) rec[i] = bedges[base + i];
    deg[t] = 0;
    __syncthreads();                 // all record loads done before any csr write
    for (int i = t; i < cnt; i += 512) atomicAdd(&deg[(rec[i] >> 17) & (BNODES - 1)], 1);
    __syncthreads();
    const int d = (t < nn) ? deg[t] : 0;
    const int pd = (d + 7) & ~7;     // pad each segment to x8
    offx[t] = pd; __syncthreads();
    for (int off = 1; off < BNODES; off <<= 1) {
        int a = (t >= off) ? offx[t - off] : 0;
        __syncthreads(); offx[t] += a; __syncthreads();
    }
    const int myoff = offx[t] - pd;  // exclusive
    cur[t] = myoff;
    if (t < nn) {
        offs[vb + t] = base + myoff;
        deg_c[vb + t] = d;
        dinv[vb + t] = (d > 0) ? rsqrtf((float)d) : 0.0f;
        for (int j = d; j < pd; j++) csr[base + myoff + j] = N_NODES;  // sentinel
    }
    __syncthreads();
    for (int i = t; i < cnt; i += 512) {
        const int r = rec[i];
        const int pos = atomicAdd(&cur[(r >> 17) & (BNODES - 1)], 1);
        csr[base + pos] = r & 0x1FFFF;
    }
}

// ---------------- register-tiled GEMM: H[n] = dinv[n] * (X[n,:] @ W) ----------------
// 64-node x 64-channel block tile, 256 threads, 4x4 register tile per thread.
// K chunked at 64. Per k: 1 ds_read_b128 (W) + 4 broadcast ds_read_b32 (x) + 16 FMA.

template <int CIN>
__global__ __launch_bounds__(256) void k_gemm(const float* __restrict__ X,
                                              const float* __restrict__ W,
                                              const float* __restrict__ dinv,
                                              float* __restrict__ H) {
    constexpr int STR = 68;                     // node-row stride (floats), pad 4
    __shared__ float sX[64 * STR];              // [node][k-chunk]
    __shared__ float sW[64 * 64];               // [k][c]
    const int t = threadIdx.x;
    const int nb = blockIdx.x * 64;
    const int tx = t & 15;                      // channel group: c0 = tx*4
    const int ty = t >> 4;                      // node group:    n0 = ty*4
    const int c0 = tx * 4, n0 = ty * 4;

    float acc[4][4] = {};

    for (int k0 = 0; k0 < CIN; k0 += 64) {
        if (k0) __syncthreads();
        // stage W chunk [64 x 64], direct float4 copy (k-major, matches input)
        for (int i = t; i < 64 * 16; i += 256) {
            const int k = i >> 4, c4 = (i & 15) * 4;
            *reinterpret_cast<float4*>(&sW[k * 64 + c4]) =
                *reinterpret_cast<const float4*>(W + (size_t)(k0 + k) * 64 + c4);
        }
        // stage X chunk [64 nodes x 64 k], coalesced float4, node-major
        for (int i = t; i < 64 * 16; i += 256) {
            const int node = i >> 4, k4 = (i & 15) * 4;
            const int gn = nb + node;
            float4 v = make_float4(0.f, 0.f, 0.f, 0.f);
            if (gn < N_NODES)
                v = *reinterpret_cast<const float4*>(X + (size_t)gn * CIN + k0 + k4);
            *reinterpret_cast<float4*>(&sX[node * STR + k4]) = v;
        }
        __syncthreads();

        const float* xb = &sX[n0 * STR];
        #pragma unroll 4
        for (int k = 0; k < 64; k++) {
            const float4 b = *reinterpret_cast<const float4*>(&sW[k * 64 + c0]);
            const float a0 = xb[k];
            const float a1 = xb[STR + k];
            const float a2 = xb[2 * STR + k];
            const float a3 = xb[3 * STR + k];
            acc[0][0] += a0 * b.x; acc[0][1] += a0 * b.y; acc[0][2] += a0 * b.z; acc[0][3] += a0 * b.w;
            acc[1][0] += a1 * b.x; acc[1][1] += a1 * b.y; acc[1][2] += a1 * b.z; acc[1][3] += a1 * b.w;
            acc[2][0] += a2 * b.x; acc[2][1] += a2 * b.y; acc[2][2] += a2 * b.z; acc[2][3] += a2 * b.w;
            acc[3][0] += a3 * b.x; acc[3][1] += a3 * b.y; acc[3][2] += a3 * b.z; acc[3][3] += a3 * b.w;
        }
    }

    #pragma unroll
    for (int n = 0; n < 4; n++) {
        const int gn = nb + n0 + n;
        if (gn < N_NODES) {
            const float dv = dinv[gn];
            float4 o;
            o.x = acc[n][0] * dv; o.y = acc[n][1] * dv;
            o.z = acc[n][2] * dv; o.w = acc[n][3] * dv;
            *reinterpret_cast<float4*>(H + (size_t)gn * 64 + c0) = o;
        }
    }
}

// ---------------- propagation: Hout[v] = dinv[v] * sum_e Hin[row_e] + bias ----------------

__global__ __launch_bounds__(256) void k_prop(const float* __restrict__ Hin,
                                              const int* __restrict__ csr,
                                              const int* __restrict__ offs,
                                              const int* __restrict__ deg_c,
                                              const float* __restrict__ dinv,
                                              const float* __restrict__ bias,
                                              float* __restrict__ Hout) {
    const int wave = threadIdx.x >> 6, lane = threadIdx.x & 63;
    const int v = blockIdx.x * 4 + wave;
    if (v >= N_NODES) return;
    const int start = offs[v];                 // multiple of 8 -> 32B aligned
    const int cntp = (deg_c[v] + 7) & ~7;
    const int* ep = csr + start;
    float acc = 0.f;
    for (int j = 0; j < cntp; j += 8) {
        const int4 q0 = *reinterpret_cast<const int4*>(ep + j);
        const int4 q1 = *reinterpret_cast<const int4*>(ep + j + 4);
        float s0 = Hin[(size_t)q0.x * 64 + lane];
        float s1 = Hin[(size_t)q0.y * 64 + lane];
        float s2 = Hin[(size_t)q0.z * 64 + lane];
        float s3 = Hin[(size_t)q0.w * 64 + lane];
        float s4 = Hin[(size_t)q1.x * 64 + lane];
        float s5 = Hin[(size_t)q1.y * 64 + lane];
        float s6 = Hin[(size_t)q1.z * 64 + lane];
        float s7 = Hin[(size_t)q1.w * 64 + lane];
        acc += ((s0 + s1) + (s2 + s3)) + ((s4 + s5) + (s6 + s7));
    }
    Hout[(size_t)v * 64 + lane] = dinv[v] * acc + bias[lane];
}

// ---------------- pooling: one (graph, split) block; atomic-free partials ----------------

__global__ __launch_bounds__(256) void k_pool(const float* __restrict__ H,
                                              const int* __restrict__ batch,
                                              float* __restrict__ partial) {
    const int g = blockIdx.x >> 2;           // graph
    const int s = blockIdx.x & (SPLIT - 1);  // split
    int lo = 0, hi = N_NODES;
    while (lo < hi) { int m = (lo + hi) >> 1; if (batch[m] < g) lo = m + 1; else hi = m; }
    const int a = lo;
    lo = 0; hi = N_NODES;
    while (lo < hi) { int m = (lo + hi) >> 1; if (batch[m] < g + 1) lo = m + 1; else hi = m; }
    const int b = lo;

    const int wave = threadIdx.x >> 6, lane = threadIdx.x & 63;
    const int lane16 = s * 4 + wave;         // 0..15: stride position
    float ac0 = 0.f, ac1 = 0.f, ac2 = 0.f, ac3 = 0.f;
    int v = a + lane16;
    for (; v + 48 < b; v += 64) {            // 4 independent loads in flight
        ac0 += H[(size_t)v * 64 + lane];
        ac1 += H[(size_t)(v + 16) * 64 + lane];
        ac2 += H[(size_t)(v + 32) * 64 + lane];
        ac3 += H[(size_t)(v + 48) * 64 + lane];
    }
    for (; v < b; v += 16) ac0 += H[(size_t)v * 64 + lane];
    const float acc = (ac0 + ac1) + (ac2 + ac3);

    __shared__ float red[4][64];
    red[wave][lane] = acc;
    __syncthreads();
    if (wave == 0) {
        const float r = (red[0][lane] + red[1][lane]) + (red[2][lane] + red[3][lane]);
        partial[((size_t)s * N_GRAPHS + g) * 64 + lane] = r;
    }
}

__global__ void k_final(const float* __restrict__ partial, const int* __restrict__ batch,
                        const float* __restrict__ Wl, const float* __restrict__ bl,
                        float* __restrict__ out) {
    __shared__ int scnt[128];
    int t = threadIdx.x;
    int lo = 0, hi = N_NODES;
    while (lo < hi) { int mid = (lo + hi) >> 1; if (batch[mid] < t) lo = mid + 1; else hi = mid; }
    int a = lo;
    lo = 0; hi = N_NODES;
    while (lo < hi) { int mid = (lo + hi) >> 1; if (batch[mid] < t + 1) lo = mid + 1; else hi = mid; }
    scnt[t] = lo - a;
    __syncthreads();
    for (int off = 64; off > 0; off >>= 1) {
        if (t < off) scnt[t] = max(scnt[t], scnt[t + off]);
        __syncthreads();
    }
    const float nmax = (float)scnt[0];
    float s = 0.f;
    for (int c = 0; c < 64; c++) {
        float g = 0.f;
        #pragma unroll
        for (int p = 0; p < SPLIT; p++)
            g += partial[((size_t)p * N_GRAPHS + t) * 64 + c];
        s += g * Wl[c];
    }
    out[t] = s / nmax + bl[0];
}

// ---------------- launch ----------------

extern "C" void kernel_launch(void* const* d_in, const int* in_sizes, int n_in,
                              void* d_out, int out_size, void* d_ws, size_t ws_size,
                              hipStream_t stream) {
    const float* x    = (const float*)d_in[0];
    const int*   ei   = (const int*)d_in[1];     // [2, E] int32
    const int*   batch= (const int*)d_in[2];
    const float* W1 = (const float*)d_in[3];  const float* b1 = (const float*)d_in[4];
    const float* W2 = (const float*)d_in[5];  const float* b2 = (const float*)d_in[6];
    const float* W3 = (const float*)d_in[7];  const float* b3 = (const float*)d_in[8];
    const float* W4 = (const float*)d_in[9];  const float* b4 = (const float*)d_in[10];
    const float* Wl = (const float*)d_in[11]; const float* bl = (const float*)d_in[12];
    float* out = (float*)d_out;

    const int* row = ei;
    const int* col = ei + N_EDGES;

    // workspace layout (256B aligned blocks)
    char* ws = (char*)d_ws;
    size_t off = 0;
    auto alloc = [&](size_t bytes) {
        void* p = ws + off;
        off = (off + bytes + 255) & ~(size_t)255;
        return p;
    };
    int*   hist_t  = (int*)alloc((size_t)NB * BLK * 4);
    int*   cursors = (int*)alloc((size_t)NB * BLK * 4);
    int*   bcnt    = (int*)alloc(NB * 4);
    int*   bedges  = (int*)alloc((size_t)NB * CAP * 4);   // aliased by csr
    int*   csr     = bedges;                              // in-place rebuild (safe)
    int*   offs    = (int*)alloc(N_NODES * 4);
    int*   deg_c   = (int*)alloc(N_NODES * 4);
    float* dinv    = (float*)alloc(N_NODES * 4);
    float* h_a     = (float*)alloc((size_t)(N_NODES + 1) * 64 * 4);   // +1 zero row
    float* h_b     = (float*)alloc((size_t)(N_NODES + 1) * 64 * 4);
    float* partial = (float*)alloc((size_t)SPLIT * N_GRAPHS * 64 * 4);

    hipMemsetAsync(h_a + (size_t)N_NODES * 64, 0, 64 * 4, stream);
    hipMemsetAsync(h_b + (size_t)N_NODES * 64, 0, 64 * 4, stream);

    // CSR build: histogram -> cursors -> bucket scatter -> per-bucket build
    k_hist<<<BLK, 256, 0, stream>>>(col, hist_t);
    k_cursors<<<NB, 512, 0, stream>>>(hist_t, cursors, bcnt);
    k_mid<<<BLK, 256, 0, stream>>>(row, col, cursors, bedges);
    k_build<<<NB, 512, 0, stream>>>(bedges, bcnt, csr, offs, deg_c, dinv);

    const int GB = (N_NODES + 63) / 64;   // 1563 gemm blocks

    // layer 1: h_a = dinv * (x @ W1) ; h_b = dinv * prop(h_a) + b1
    k_gemm<128><<<GB, 256, 0, stream>>>(x, W1, dinv, h_a);
    k_prop<<<N_NODES / 4, 256, 0, stream>>>(h_a, csr, offs, deg_c, dinv, b1, h_b);
    // layer 2
    k_gemm<64><<<GB, 256, 0, stream>>>(h_b, W2, dinv, h_a);
    k_prop<<<N_NODES / 4, 256, 0, stream>>>(h_a, csr, offs, deg_c, dinv, b2, h_b);
    // layer 3
    k_gemm<64><<<GB, 256, 0, stream>>>(h_b, W3, dinv, h_a);
    k_prop<<<N_NODES / 4, 256, 0, stream>>>(h_a, csr, offs, deg_c, dinv, b3, h_b);
    // layer 4
    k_gemm<64><<<GB, 256, 0, stream>>>(h_b, W4, dinv, h_a);
    k_prop<<<N_NODES / 4, 256, 0, stream>>>(h_a, csr, offs, deg_c, dinv, b4, h_b);

    // pooling + readout (atomic-free)
    k_pool<<<N_GRAPHS * SPLIT, 256, 0, stream>>>(h_b, batch, partial);
    k_final<<<1, 128, 0, stream>>>(partial, batch, Wl, bl, out);
}

// Round 8
// 463.302 us; speedup vs baseline: 1.7206x; 1.0604x over previous
//
#include <hip/hip_runtime.h>
#include <hip/hip_bf16.h>
#include <hip/hip_fp16.h>

// Problem constants (match reference)
#define N_NODES 100000
#define N_EDGES 1600000
#define N_GRAPHS 128

// Counting-sort CSR build parameters
#define BSH 9                 // bucket = col >> 9
#define BNODES 512            // nodes per bucket
#define NB 196                // ceil(100000 / 512)
#define CAP 12288             // static per-bucket csr/record capacity (elems)
#define BLK 512               // histogram blocks
#define EPB (N_EDGES / BLK)   // 3125 edges per block (exact)
#define RECMAX 10240          // max records per bucket held in LDS

#define SPLIT 4               // pooling blocks per graph

// ---------------- CSR build (no global atomics) ----------------

__global__ __launch_bounds__(256) void k_hist(const int* __restrict__ col,
                                              int* __restrict__ hist_t) {
    __shared__ int h[NB];
    const int t = threadIdx.x, b = blockIdx.x;
    for (int i = t; i < NB; i += 256) h[i] = 0;
    __syncthreads();
    const int e0 = b * EPB;
    for (int i = t; i < EPB; i += 256) atomicAdd(&h[col[e0 + i] >> BSH], 1);
    __syncthreads();
    for (int i = t; i < NB; i += 256) hist_t[i * BLK + b] = h[i];
}

__global__ __launch_bounds__(512) void k_cursors(const int* __restrict__ hist_t,
                                                 int* __restrict__ cursors,
                                                 int* __restrict__ bcnt) {
    __shared__ int s[BLK];
    const int t = threadIdx.x, bin = blockIdx.x;
    const int v = hist_t[bin * BLK + t];
    s[t] = v; __syncthreads();
    for (int off = 1; off < BLK; off <<= 1) {
        int a = (t >= off) ? s[t - off] : 0;
        __syncthreads(); s[t] += a; __syncthreads();
    }
    cursors[bin * BLK + t] = bin * CAP + s[t] - v;   // exclusive + static base
    if (t == BLK - 1) bcnt[bin] = s[t];
}

__global__ __launch_bounds__(256) void k_mid(const int* __restrict__ row,
                                             const int* __restrict__ col,
                                             const int* __restrict__ cursors,
                                             int* __restrict__ bedges) {
    __shared__ int cur[NB];
    const int t = threadIdx.x, b = blockIdx.x;
    for (int i = t; i < NB; i += 256) cur[i] = cursors[i * BLK + b];
    __syncthreads();
    const int e0 = b * EPB;
    for (int i = t; i < EPB; i += 256) {
        const int c = col[e0 + i];
        const int r = row[e0 + i];
        const int pos = atomicAdd(&cur[c >> BSH], 1);
        bedges[pos] = r | ((c & (BNODES - 1)) << 17);   // row<2^17, lcol 9 bits
    }
}

__global__ __launch_bounds__(512) void k_build(const int* __restrict__ bedges,
                                               const int* __restrict__ bcnt,
                                               int* __restrict__ csr,
                                               int* __restrict__ offs,
                                               int* __restrict__ deg_c,
                                               float* __restrict__ dinv) {
    __shared__ int rec[RECMAX];
    __shared__ int deg[BNODES];
    __shared__ int offx[BNODES];
    __shared__ int cur[BNODES];
    const int t = threadIdx.x, bin = blockIdx.x;
    const int base = bin * CAP;
    const int cnt = bcnt[bin];
    const int vb = bin << BSH;
    const int nn = min(BNODES, N_NODES - vb);
    for (int i = t; i < cnt; i += 512) rec[i] = bedges[base + i];
    deg[t] = 0;
    __syncthreads();                 // all record loads done before any csr write
    for (int i = t; i < cnt; i += 512) atomicAdd(&deg[(rec[i] >> 17) & (BNODES - 1)], 1);
    __syncthreads();
    const int d = (t < nn) ? deg[t] : 0;
    const int pd = (d + 7) & ~7;     // pad each segment to x8
    offx[t] = pd; __syncthreads();
    for (int off = 1; off < BNODES; off <<= 1) {
        int a = (t >= off) ? offx[t - off] : 0;
        __syncthreads(); offx[t] += a; __syncthreads();
    }
    const int myoff = offx[t] - pd;  // exclusive
    cur[t] = myoff;
    if (t < nn) {
        offs[vb + t] = base + myoff;
        deg_c[vb + t] = d;
        dinv[vb + t] = (d > 0) ? rsqrtf((float)d) : 0.0f;
        for (int j = d; j < pd; j++) csr[base + myoff + j] = N_NODES;  // sentinel
    }
    __syncthreads();
    for (int i = t; i < cnt; i += 512) {
        const int r = rec[i];
        const int pos = atomicAdd(&cur[(r >> 17) & (BNODES - 1)], 1);
        csr[base + pos] = r & 0x1FFFF;
    }
}

// ---------------- register-tiled GEMM: H16[n] = fp16(dinv[n] * (X[n,:] @ W)) ----------------
// 64-node x 64-channel block tile, 256 threads, 4x4 register tile per thread.
// fp32 input/accumulate; single fp16 rounding on store (gather-table compression).

template <int CIN>
__global__ __launch_bounds__(256) void k_gemm(const float* __restrict__ X,
                                              const float* __restrict__ W,
                                              const float* __restrict__ dinv,
                                              __half* __restrict__ H16) {
    constexpr int STR = 68;                     // node-row stride (floats), pad 4
    __shared__ float sX[64 * STR];              // [node][k-chunk]
    __shared__ float sW[64 * 64];               // [k][c]
    const int t = threadIdx.x;
    const int nb = blockIdx.x * 64;
    const int tx = t & 15;                      // channel group: c0 = tx*4
    const int ty = t >> 4;                      // node group:    n0 = ty*4
    const int c0 = tx * 4, n0 = ty * 4;

    float acc[4][4] = {};

    for (int k0 = 0; k0 < CIN; k0 += 64) {
        if (k0) __syncthreads();
        for (int i = t; i < 64 * 16; i += 256) {
            const int k = i >> 4, c4 = (i & 15) * 4;
            *reinterpret_cast<float4*>(&sW[k * 64 + c4]) =
                *reinterpret_cast<const float4*>(W + (size_t)(k0 + k) * 64 + c4);
        }
        for (int i = t; i < 64 * 16; i += 256) {
            const int node = i >> 4, k4 = (i & 15) * 4;
            const int gn = nb + node;
            float4 v = make_float4(0.f, 0.f, 0.f, 0.f);
            if (gn < N_NODES)
                v = *reinterpret_cast<const float4*>(X + (size_t)gn * CIN + k0 + k4);
            *reinterpret_cast<float4*>(&sX[node * STR + k4]) = v;
        }
        __syncthreads();

        const float* xb = &sX[n0 * STR];
        #pragma unroll 4
        for (int k = 0; k < 64; k++) {
            const float4 b = *reinterpret_cast<const float4*>(&sW[k * 64 + c0]);
            const float a0 = xb[k];
            const float a1 = xb[STR + k];
            const float a2 = xb[2 * STR + k];
            const float a3 = xb[3 * STR + k];
            acc[0][0] += a0 * b.x; acc[0][1] += a0 * b.y; acc[0][2] += a0 * b.z; acc[0][3] += a0 * b.w;
            acc[1][0] += a1 * b.x; acc[1][1] += a1 * b.y; acc[1][2] += a1 * b.z; acc[1][3] += a1 * b.w;
            acc[2][0] += a2 * b.x; acc[2][1] += a2 * b.y; acc[2][2] += a2 * b.z; acc[2][3] += a2 * b.w;
            acc[3][0] += a3 * b.x; acc[3][1] += a3 * b.y; acc[3][2] += a3 * b.z; acc[3][3] += a3 * b.w;
        }
    }

    #pragma unroll
    for (int n = 0; n < 4; n++) {
        const int gn = nb + n0 + n;
        if (gn < N_NODES) {
            const float dv = dinv[gn];
            const __half2 p0 = __floats2half2_rn(acc[n][0] * dv, acc[n][1] * dv);
            const __half2 p1 = __floats2half2_rn(acc[n][2] * dv, acc[n][3] * dv);
            __half2* dst = reinterpret_cast<__half2*>(H16 + (size_t)gn * 64 + c0);
            dst[0] = p0; dst[1] = p1;
        }
    }
}

// ---------------- propagation: Hout[v] = dinv[v] * sum_e fp32(H16[row_e]) + bias --------

__global__ __launch_bounds__(256) void k_prop(const __half* __restrict__ Hin,
                                              const int* __restrict__ csr,
                                              const int* __restrict__ offs,
                                              const int* __restrict__ deg_c,
                                              const float* __restrict__ dinv,
                                              const float* __restrict__ bias,
                                              float* __restrict__ Hout) {
    const int wave = threadIdx.x >> 6, lane = threadIdx.x & 63;
    const int v = blockIdx.x * 4 + wave;
    if (v >= N_NODES) return;
    const int start = offs[v];                 // multiple of 8 -> 32B aligned
    const int cntp = (deg_c[v] + 7) & ~7;
    const int* ep = csr + start;
    float acc = 0.f;
    for (int j = 0; j < cntp; j += 8) {
        const int4 q0 = *reinterpret_cast<const int4*>(ep + j);
        const int4 q1 = *reinterpret_cast<const int4*>(ep + j + 4);
        float s0 = __half2float(Hin[(size_t)q0.x * 64 + lane]);
        float s1 = __half2float(Hin[(size_t)q0.y * 64 + lane]);
        float s2 = __half2float(Hin[(size_t)q0.z * 64 + lane]);
        float s3 = __half2float(Hin[(size_t)q0.w * 64 + lane]);
        float s4 = __half2float(Hin[(size_t)q1.x * 64 + lane]);
        float s5 = __half2float(Hin[(size_t)q1.y * 64 + lane]);
        float s6 = __half2float(Hin[(size_t)q1.z * 64 + lane]);
        float s7 = __half2float(Hin[(size_t)q1.w * 64 + lane]);
        acc += ((s0 + s1) + (s2 + s3)) + ((s4 + s5) + (s6 + s7));
    }
    Hout[(size_t)v * 64 + lane] = dinv[v] * acc + bias[lane];
}

// ---------------- pooling: one (graph, split) block; atomic-free partials ----------------

__global__ __launch_bounds__(256) void k_pool(const float* __restrict__ H,
                                              const int* __restrict__ batch,
                                              float* __restrict__ partial) {
    const int g = blockIdx.x >> 2;           // graph
    const int s = blockIdx.x & (SPLIT - 1);  // split
    int lo = 0, hi = N_NODES;
    while (lo < hi) { int m = (lo + hi) >> 1; if (batch[m] < g) lo = m + 1; else hi = m; }
    const int a = lo;
    lo = 0; hi = N_NODES;
    while (lo < hi) { int m = (lo + hi) >> 1; if (batch[m] < g + 1) lo = m + 1; else hi = m; }
    const int b = lo;

    const int wave = threadIdx.x >> 6, lane = threadIdx.x & 63;
    const int lane16 = s * 4 + wave;         // 0..15: stride position
    float ac0 = 0.f, ac1 = 0.f, ac2 = 0.f, ac3 = 0.f;
    int v = a + lane16;
    for (; v + 48 < b; v += 64) {            // 4 independent loads in flight
        ac0 += H[(size_t)v * 64 + lane];
        ac1 += H[(size_t)(v + 16) * 64 + lane];
        ac2 += H[(size_t)(v + 32) * 64 + lane];
        ac3 += H[(size_t)(v + 48) * 64 + lane];
    }
    for (; v < b; v += 16) ac0 += H[(size_t)v * 64 + lane];
    const float acc = (ac0 + ac1) + (ac2 + ac3);

    __shared__ float red[4][64];
    red[wave][lane] = acc;
    __syncthreads();
    if (wave == 0) {
        const float r = (red[0][lane] + red[1][lane]) + (red[2][lane] + red[3][lane]);
        partial[((size_t)s * N_GRAPHS + g) * 64 + lane] = r;
    }
}

__global__ void k_final(const float* __restrict__ partial, const int* __restrict__ batch,
                        const float* __restrict__ Wl, const float* __restrict__ bl,
                        float* __restrict__ out) {
    __shared__ int scnt[128];
    int t = threadIdx.x;
    int lo = 0, hi = N_NODES;
    while (lo < hi) { int mid = (lo + hi) >> 1; if (batch[mid] < t) lo = mid + 1; else hi = mid; }
    int a = lo;
    lo = 0; hi = N_NODES;
    while (lo < hi) { int mid = (lo + hi) >> 1; if (batch[mid] < t + 1) lo = mid + 1; else hi = mid; }
    scnt[t] = lo - a;
    __syncthreads();
    for (int off = 64; off > 0; off >>= 1) {
        if (t < off) scnt[t] = max(scnt[t], scnt[t + off]);
        __syncthreads();
    }
    const float nmax = (float)scnt[0];
    float s = 0.f;
    for (int c = 0; c < 64; c++) {
        float g = 0.f;
        #pragma unroll
        for (int p = 0; p < SPLIT; p++)
            g += partial[((size_t)p * N_GRAPHS + t) * 64 + c];
        s += g * Wl[c];
    }
    out[t] = s / nmax + bl[0];
}

// ---------------- launch ----------------

extern "C" void kernel_launch(void* const* d_in, const int* in_sizes, int n_in,
                              void* d_out, int out_size, void* d_ws, size_t ws_size,
                              hipStream_t stream) {
    const float* x    = (const float*)d_in[0];
    const int*   ei   = (const int*)d_in[1];     // [2, E] int32
    const int*   batch= (const int*)d_in[2];
    const float* W1 = (const float*)d_in[3];  const float* b1 = (const float*)d_in[4];
    const float* W2 = (const float*)d_in[5];  const float* b2 = (const float*)d_in[6];
    const float* W3 = (const float*)d_in[7];  const float* b3 = (const float*)d_in[8];
    const float* W4 = (const float*)d_in[9];  const float* b4 = (const float*)d_in[10];
    const float* Wl = (const float*)d_in[11]; const float* bl = (const float*)d_in[12];
    float* out = (float*)d_out;

    const int* row = ei;
    const int* col = ei + N_EDGES;

    // workspace layout (256B aligned blocks)
    char* ws = (char*)d_ws;
    size_t off = 0;
    auto alloc = [&](size_t bytes) {
        void* p = ws + off;
        off = (off + bytes + 255) & ~(size_t)255;
        return p;
    };
    int*    hist_t  = (int*)alloc((size_t)NB * BLK * 4);
    int*    cursors = (int*)alloc((size_t)NB * BLK * 4);
    int*    bcnt    = (int*)alloc(NB * 4);
    int*    bedges  = (int*)alloc((size_t)NB * CAP * 4);   // aliased by csr
    int*    csr     = bedges;                              // in-place rebuild (safe)
    int*    offs    = (int*)alloc(N_NODES * 4);
    int*    deg_c   = (int*)alloc(N_NODES * 4);
    float*  dinv    = (float*)alloc(N_NODES * 4);
    __half* h16     = (__half*)alloc((size_t)(N_NODES + 1) * 64 * 2);  // fp16 gather table (+1 zero row)
    float*  h_b     = (float*)alloc((size_t)N_NODES * 64 * 4);         // fp32 prop output
    float*  partial = (float*)alloc((size_t)SPLIT * N_GRAPHS * 64 * 4);

    hipMemsetAsync(h16 + (size_t)N_NODES * 64, 0, 64 * 2, stream);   // zero sentinel row

    // CSR build: histogram -> cursors -> bucket scatter -> per-bucket build
    k_hist<<<BLK, 256, 0, stream>>>(col, hist_t);
    k_cursors<<<NB, 512, 0, stream>>>(hist_t, cursors, bcnt);
    k_mid<<<BLK, 256, 0, stream>>>(row, col, cursors, bedges);
    k_build<<<NB, 512, 0, stream>>>(bedges, bcnt, csr, offs, deg_c, dinv);

    const int GB = (N_NODES + 63) / 64;   // 1563 gemm blocks

    // layer 1: h16 = fp16(dinv * (x @ W1)) ; h_b = dinv * prop(h16) + b1
    k_gemm<128><<<GB, 256, 0, stream>>>(x, W1, dinv, h16);
    k_prop<<<N_NODES / 4, 256, 0, stream>>>(h16, csr, offs, deg_c, dinv, b1, h_b);
    // layer 2
    k_gemm<64><<<GB, 256, 0, stream>>>(h_b, W2, dinv, h16);
    k_prop<<<N_NODES / 4, 256, 0, stream>>>(h16, csr, offs, deg_c, dinv, b2, h_b);
    // layer 3
    k_gemm<64><<<GB, 256, 0, stream>>>(h_b, W3, dinv, h16);
    k_prop<<<N_NODES / 4, 256, 0, stream>>>(h16, csr, offs, deg_c, dinv, b3, h_b);
    // layer 4
    k_gemm<64><<<GB, 256, 0, stream>>>(h_b, W4, dinv, h16);
    k_prop<<<N_NODES / 4, 256, 0, stream>>>(h16, csr, offs, deg_c, dinv, b4, h_b);

    // pooling + readout (atomic-free)
    k_pool<<<N_GRAPHS * SPLIT, 256, 0, stream>>>(h_b, batch, partial);
    k_final<<<1, 128, 0, stream>>>(partial, batch, Wl, bl, out);
}

// Round 9
// 447.127 us; speedup vs baseline: 1.7828x; 1.0362x over previous
//
#include <hip/hip_runtime.h>
#include <hip/hip_bf16.h>
#include <hip/hip_fp16.h>

// Problem constants (match reference)
#define N_NODES 100000
#define N_EDGES 1600000
#define N_GRAPHS 128

// Counting-sort CSR build parameters
#define BSH 9                 // bucket = col >> 9
#define BNODES 512            // nodes per bucket
#define NB 196                // ceil(100000 / 512)
#define CAP 12288             // static per-bucket csr/record capacity (elems)
#define BLK 512               // histogram blocks
#define EPB (N_EDGES / BLK)   // 3125 edges per block (exact)
#define RECMAX 10240          // max records per bucket held in LDS

#define SPLIT 4               // pooling blocks per graph

// ---------------- CSR build (no global atomics) ----------------

__global__ __launch_bounds__(256) void k_hist(const int* __restrict__ col,
                                              int* __restrict__ hist_t) {
    __shared__ int h[NB];
    const int t = threadIdx.x, b = blockIdx.x;
    for (int i = t; i < NB; i += 256) h[i] = 0;
    __syncthreads();
    const int e0 = b * EPB;
    for (int i = t; i < EPB; i += 256) atomicAdd(&h[col[e0 + i] >> BSH], 1);
    __syncthreads();
    for (int i = t; i < NB; i += 256) hist_t[i * BLK + b] = h[i];
}

__global__ __launch_bounds__(512) void k_cursors(const int* __restrict__ hist_t,
                                                 int* __restrict__ cursors,
                                                 int* __restrict__ bcnt) {
    __shared__ int s[BLK];
    const int t = threadIdx.x, bin = blockIdx.x;
    const int v = hist_t[bin * BLK + t];
    s[t] = v; __syncthreads();
    for (int off = 1; off < BLK; off <<= 1) {
        int a = (t >= off) ? s[t - off] : 0;
        __syncthreads(); s[t] += a; __syncthreads();
    }
    cursors[bin * BLK + t] = bin * CAP + s[t] - v;   // exclusive + static base
    if (t == BLK - 1) bcnt[bin] = s[t];
}

__global__ __launch_bounds__(256) void k_mid(const int* __restrict__ row,
                                             const int* __restrict__ col,
                                             const int* __restrict__ cursors,
                                             int* __restrict__ bedges) {
    __shared__ int cur[NB];
    const int t = threadIdx.x, b = blockIdx.x;
    for (int i = t; i < NB; i += 256) cur[i] = cursors[i * BLK + b];
    __syncthreads();
    const int e0 = b * EPB;
    for (int i = t; i < EPB; i += 256) {
        const int c = col[e0 + i];
        const int r = row[e0 + i];
        const int pos = atomicAdd(&cur[c >> BSH], 1);
        bedges[pos] = r | ((c & (BNODES - 1)) << 17);   // row<2^17, lcol 9 bits
    }
}

__global__ __launch_bounds__(512) void k_build(const int* __restrict__ bedges,
                                               const int* __restrict__ bcnt,
                                               int* __restrict__ csr,
                                               int* __restrict__ offs,
                                               int* __restrict__ deg_c,
                                               float* __restrict__ dinv) {
    __shared__ int rec[RECMAX];
    __shared__ int deg[BNODES];
    __shared__ int offx[BNODES];
    __shared__ int cur[BNODES];
    const int t = threadIdx.x, bin = blockIdx.x;
    const int base = bin * CAP;
    const int cnt = bcnt[bin];
    const int vb = bin << BSH;
    const int nn = min(BNODES, N_NODES - vb);
    for (int i = t; i < cnt; i += 512) rec[i] = bedges[base + i];
    deg[t] = 0;
    __syncthreads();                 // all record loads done before any csr write
    for (int i = t; i < cnt; i += 512) atomicAdd(&deg[(rec[i] >> 17) & (BNODES - 1)], 1);
    __syncthreads();
    const int d = (t < nn) ? deg[t] : 0;
    const int pd = (d + 7) & ~7;     // pad each segment to x8
    offx[t] = pd; __syncthreads();
    for (int off = 1; off < BNODES; off <<= 1) {
        int a = (t >= off) ? offx[t - off] : 0;
        __syncthreads(); offx[t] += a; __syncthreads();
    }
    const int myoff = offx[t] - pd;  // exclusive
    cur[t] = myoff;
    if (t < nn) {
        offs[vb + t] = base + myoff;
        deg_c[vb + t] = d;
        dinv[vb + t] = (d > 0) ? rsqrtf((float)d) : 0.0f;
        for (int j = d; j < pd; j++) csr[base + myoff + j] = N_NODES;  // sentinel
    }
    __syncthreads();
    for (int i = t; i < cnt; i += 512) {
        const int r = rec[i];
        const int pos = atomicAdd(&cur[(r >> 17) & (BNODES - 1)], 1);
        csr[base + pos] = r & 0x1FFFF;
    }
}

// ---------------- register-tiled GEMM: H16[n] = fp16(dinv[n] * (X[n,:] @ W)) ----------------

template <int CIN>
__global__ __launch_bounds__(256) void k_gemm(const float* __restrict__ X,
                                              const float* __restrict__ W,
                                              const float* __restrict__ dinv,
                                              __half* __restrict__ H16) {
    constexpr int STR = 68;                     // node-row stride (floats), pad 4
    __shared__ float sX[64 * STR];              // [node][k-chunk]
    __shared__ float sW[64 * 64];               // [k][c]
    const int t = threadIdx.x;
    const int nb = blockIdx.x * 64;
    const int tx = t & 15;                      // channel group: c0 = tx*4
    const int ty = t >> 4;                      // node group:    n0 = ty*4
    const int c0 = tx * 4, n0 = ty * 4;

    float acc[4][4] = {};

    for (int k0 = 0; k0 < CIN; k0 += 64) {
        if (k0) __syncthreads();
        for (int i = t; i < 64 * 16; i += 256) {
            const int k = i >> 4, c4 = (i & 15) * 4;
            *reinterpret_cast<float4*>(&sW[k * 64 + c4]) =
                *reinterpret_cast<const float4*>(W + (size_t)(k0 + k) * 64 + c4);
        }
        for (int i = t; i < 64 * 16; i += 256) {
            const int node = i >> 4, k4 = (i & 15) * 4;
            const int gn = nb + node;
            float4 v = make_float4(0.f, 0.f, 0.f, 0.f);
            if (gn < N_NODES)
                v = *reinterpret_cast<const float4*>(X + (size_t)gn * CIN + k0 + k4);
            *reinterpret_cast<float4*>(&sX[node * STR + k4]) = v;
        }
        __syncthreads();

        const float* xb = &sX[n0 * STR];
        #pragma unroll 4
        for (int k = 0; k < 64; k++) {
            const float4 b = *reinterpret_cast<const float4*>(&sW[k * 64 + c0]);
            const float a0 = xb[k];
            const float a1 = xb[STR + k];
            const float a2 = xb[2 * STR + k];
            const float a3 = xb[3 * STR + k];
            acc[0][0] += a0 * b.x; acc[0][1] += a0 * b.y; acc[0][2] += a0 * b.z; acc[0][3] += a0 * b.w;
            acc[1][0] += a1 * b.x; acc[1][1] += a1 * b.y; acc[1][2] += a1 * b.z; acc[1][3] += a1 * b.w;
            acc[2][0] += a2 * b.x; acc[2][1] += a2 * b.y; acc[2][2] += a2 * b.z; acc[2][3] += a2 * b.w;
            acc[3][0] += a3 * b.x; acc[3][1] += a3 * b.y; acc[3][2] += a3 * b.z; acc[3][3] += a3 * b.w;
        }
    }

    #pragma unroll
    for (int n = 0; n < 4; n++) {
        const int gn = nb + n0 + n;
        if (gn < N_NODES) {
            const float dv = dinv[gn];
            const __half2 p0 = __floats2half2_rn(acc[n][0] * dv, acc[n][1] * dv);
            const __half2 p1 = __floats2half2_rn(acc[n][2] * dv, acc[n][3] * dv);
            __half2* dst = reinterpret_cast<__half2*>(H16 + (size_t)gn * 64 + c0);
            dst[0] = p0; dst[1] = p1;
        }
    }
}

// ---------------- propagation: Hout[v] = dinv[v] * sum_e fp32(H16[row_e]) + bias --------
// wave per node; lane = channel PAIR (half2, 4B/lane); the two half-waves
// process even/odd edges concurrently -> 4 VMEM per 8 edges.

__global__ __launch_bounds__(256) void k_prop(const __half* __restrict__ Hin,
                                              const int* __restrict__ csr,
                                              const int* __restrict__ offs,
                                              const int* __restrict__ deg_c,
                                              const float* __restrict__ dinv,
                                              const float* __restrict__ bias,
                                              float* __restrict__ Hout) {
    const int wave = threadIdx.x >> 6, lane = threadIdx.x & 63;
    const int v = blockIdx.x * 4 + wave;
    if (v >= N_NODES) return;
    const int c2 = lane & 31;              // channel pair: channels 2*c2, 2*c2+1
    const int half = lane >> 5;            // edge parity for this half-wave
    const int start = offs[v];             // multiple of 8 -> 32B aligned
    const int cntp = (deg_c[v] + 7) & ~7;
    const int* ep = csr + start;
    const __half* hb = Hin + c2 * 2;
    float ax = 0.f, ay = 0.f;
    for (int j = 0; j < cntp; j += 8) {
        const int4 q0 = *reinterpret_cast<const int4*>(ep + j);      // broadcast
        const int4 q1 = *reinterpret_cast<const int4*>(ep + j + 4);
        const int i0 = half ? q0.y : q0.x;
        const int i1 = half ? q0.w : q0.z;
        const int i2 = half ? q1.y : q1.x;
        const int i3 = half ? q1.w : q1.z;
        const __half2 h0 = *reinterpret_cast<const __half2*>(hb + (size_t)i0 * 64);
        const __half2 h1 = *reinterpret_cast<const __half2*>(hb + (size_t)i1 * 64);
        const __half2 h2 = *reinterpret_cast<const __half2*>(hb + (size_t)i2 * 64);
        const __half2 h3 = *reinterpret_cast<const __half2*>(hb + (size_t)i3 * 64);
        const float2 f0 = __half22float2(h0);
        const float2 f1 = __half22float2(h1);
        const float2 f2 = __half22float2(h2);
        const float2 f3 = __half22float2(h3);
        ax += (f0.x + f1.x) + (f2.x + f3.x);
        ay += (f0.y + f1.y) + (f2.y + f3.y);
    }
    // combine even/odd half-wave partials (lane ^ 32 holds the other parity)
    ax += __shfl_xor(ax, 32, 64);
    ay += __shfl_xor(ay, 32, 64);
    if (half == 0) {
        const float dv = dinv[v];
        float2 o;
        o.x = dv * ax + bias[c2 * 2];
        o.y = dv * ay + bias[c2 * 2 + 1];
        *reinterpret_cast<float2*>(Hout + (size_t)v * 64 + c2 * 2) = o;
    }
}

// ---------------- pooling: one (graph, split) block; atomic-free partials ----------------

__global__ __launch_bounds__(256) void k_pool(const float* __restrict__ H,
                                              const int* __restrict__ batch,
                                              float* __restrict__ partial) {
    const int g = blockIdx.x >> 2;           // graph
    const int s = blockIdx.x & (SPLIT - 1);  // split
    int lo = 0, hi = N_NODES;
    while (lo < hi) { int m = (lo + hi) >> 1; if (batch[m] < g) lo = m + 1; else hi = m; }
    const int a = lo;
    lo = 0; hi = N_NODES;
    while (lo < hi) { int m = (lo + hi) >> 1; if (batch[m] < g + 1) lo = m + 1; else hi = m; }
    const int b = lo;

    const int wave = threadIdx.x >> 6, lane = threadIdx.x & 63;
    const int lane16 = s * 4 + wave;         // 0..15: stride position
    float ac0 = 0.f, ac1 = 0.f, ac2 = 0.f, ac3 = 0.f;
    int v = a + lane16;
    for (; v + 48 < b; v += 64) {            // 4 independent loads in flight
        ac0 += H[(size_t)v * 64 + lane];
        ac1 += H[(size_t)(v + 16) * 64 + lane];
        ac2 += H[(size_t)(v + 32) * 64 + lane];
        ac3 += H[(size_t)(v + 48) * 64 + lane];
    }
    for (; v < b; v += 16) ac0 += H[(size_t)v * 64 + lane];
    const float acc = (ac0 + ac1) + (ac2 + ac3);

    __shared__ float red[4][64];
    red[wave][lane] = acc;
    __syncthreads();
    if (wave == 0) {
        const float r = (red[0][lane] + red[1][lane]) + (red[2][lane] + red[3][lane]);
        partial[((size_t)s * N_GRAPHS + g) * 64 + lane] = r;
    }
}

__global__ void k_final(const float* __restrict__ partial, const int* __restrict__ batch,
                        const float* __restrict__ Wl, const float* __restrict__ bl,
                        float* __restrict__ out) {
    __shared__ int scnt[128];
    int t = threadIdx.x;
    int lo = 0, hi = N_NODES;
    while (lo < hi) { int mid = (lo + hi) >> 1; if (batch[mid] < t) lo = mid + 1; else hi = mid; }
    int a = lo;
    lo = 0; hi = N_NODES;
    while (lo < hi) { int mid = (lo + hi) >> 1; if (batch[mid] < t + 1) lo = mid + 1; else hi = mid; }
    scnt[t] = lo - a;
    __syncthreads();
    for (int off = 64; off > 0; off >>= 1) {
        if (t < off) scnt[t] = max(scnt[t], scnt[t + off]);
        __syncthreads();
    }
    const float nmax = (float)scnt[0];
    float s = 0.f;
    for (int c = 0; c < 64; c++) {
        float g = 0.f;
        #pragma unroll
        for (int p = 0; p < SPLIT; p++)
            g += partial[((size_t)p * N_GRAPHS + t) * 64 + c];
        s += g * Wl[c];
    }
    out[t] = s / nmax + bl[0];
}

// ---------------- launch ----------------

extern "C" void kernel_launch(void* const* d_in, const int* in_sizes, int n_in,
                              void* d_out, int out_size, void* d_ws, size_t ws_size,
                              hipStream_t stream) {
    const float* x    = (const float*)d_in[0];
    const int*   ei   = (const int*)d_in[1];     // [2, E] int32
    const int*   batch= (const int*)d_in[2];
    const float* W1 = (const float*)d_in[3];  const float* b1 = (const float*)d_in[4];
    const float* W2 = (const float*)d_in[5];  const float* b2 = (const float*)d_in[6];
    const float* W3 = (const float*)d_in[7];  const float* b3 = (const float*)d_in[8];
    const float* W4 = (const float*)d_in[9];  const float* b4 = (const float*)d_in[10];
    const float* Wl = (const float*)d_in[11]; const float* bl = (const float*)d_in[12];
    float* out = (float*)d_out;

    const int* row = ei;
    const int* col = ei + N_EDGES;

    // workspace layout (256B aligned blocks)
    char* ws = (char*)d_ws;
    size_t off = 0;
    auto alloc = [&](size_t bytes) {
        void* p = ws + off;
        off = (off + bytes + 255) & ~(size_t)255;
        return p;
    };
    int*    hist_t  = (int*)alloc((size_t)NB * BLK * 4);
    int*    cursors = (int*)alloc((size_t)NB * BLK * 4);
    int*    bcnt    = (int*)alloc(NB * 4);
    int*    bedges  = (int*)alloc((size_t)NB * CAP * 4);   // aliased by csr
    int*    csr     = bedges;                              // in-place rebuild (safe)
    int*    offs    = (int*)alloc(N_NODES * 4);
    int*    deg_c   = (int*)alloc(N_NODES * 4);
    float*  dinv    = (float*)alloc(N_NODES * 4);
    __half* h16     = (__half*)alloc((size_t)(N_NODES + 1) * 64 * 2);  // fp16 gather table (+1 zero row)
    float*  h_b     = (float*)alloc((size_t)N_NODES * 64 * 4);         // fp32 prop output
    float*  partial = (float*)alloc((size_t)SPLIT * N_GRAPHS * 64 * 4);

    hipMemsetAsync(h16 + (size_t)N_NODES * 64, 0, 64 * 2, stream);   // zero sentinel row

    // CSR build: histogram -> cursors -> bucket scatter -> per-bucket build
    k_hist<<<BLK, 256, 0, stream>>>(col, hist_t);
    k_cursors<<<NB, 512, 0, stream>>>(hist_t, cursors, bcnt);
    k_mid<<<BLK, 256, 0, stream>>>(row, col, cursors, bedges);
    k_build<<<NB, 512, 0, stream>>>(bedges, bcnt, csr, offs, deg_c, dinv);

    const int GB = (N_NODES + 63) / 64;   // 1563 gemm blocks

    // layer 1: h16 = fp16(dinv * (x @ W1)) ; h_b = dinv * prop(h16) + b1
    k_gemm<128><<<GB, 256, 0, stream>>>(x, W1, dinv, h16);
    k_prop<<<N_NODES / 4, 256, 0, stream>>>(h16, csr, offs, deg_c, dinv, b1, h_b);
    // layer 2
    k_gemm<64><<<GB, 256, 0, stream>>>(h_b, W2, dinv, h16);
    k_prop<<<N_NODES / 4, 256, 0, stream>>>(h16, csr, offs, deg_c, dinv, b2, h_b);
    // layer 3
    k_gemm<64><<<GB, 256, 0, stream>>>(h_b, W3, dinv, h16);
    k_prop<<<N_NODES / 4, 256, 0, stream>>>(h16, csr, offs, deg_c, dinv, b3, h_b);
    // layer 4
    k_gemm<64><<<GB, 256, 0, stream>>>(h_b, W4, dinv, h16);
    k_prop<<<N_NODES / 4, 256, 0, stream>>>(h16, csr, offs, deg_c, dinv, b4, h_b);

    // pooling + readout (atomic-free)
    k_pool<<<N_GRAPHS * SPLIT, 256, 0, stream>>>(h_b, batch, partial);
    k_final<<<1, 128, 0, stream>>>(partial, batch, Wl, bl, out);
}